// Round 1
// baseline (15847.455 us; speedup 1.0000x reference)
//
#include <hip/hip_runtime.h>

#define N_NODES 296960
#define N_EDGES 2375680
#define IN_FEATS 75
#define DIM 128
#define N_LAYERS 3

// ---------------------------------------------------------------- zero agg
__global__ void zero_f4(float4* __restrict__ p, int n4) {
    int i = blockIdx.x * blockDim.x + threadIdx.x;
    if (i < n4) p[i] = make_float4(0.f, 0.f, 0.f, 0.f);
}

// ---------------------------------------------------------------- h = X @ W_init  (K=75, no bias/relu)
__global__ void init_mm(const float* __restrict__ X, const float* __restrict__ W,
                        float* __restrict__ H) {
    __shared__ float sF[8 * IN_FEATS];
    const int tid = threadIdx.x;
    const long rowBase = (long)blockIdx.x * 8;

    for (int i = tid; i < 8 * IN_FEATS; i += 256)
        sF[i] = X[rowBase * IN_FEATS + i];
    __syncthreads();

    const int r = tid >> 5;
    const int c = (tid & 31) * 4;
    float4 acc = make_float4(0.f, 0.f, 0.f, 0.f);
    for (int k = 0; k < IN_FEATS; ++k) {
        const float a = sF[r * IN_FEATS + k];
        const float4 w = *reinterpret_cast<const float4*>(W + k * DIM + c);
        acc.x += a * w.x; acc.y += a * w.y; acc.z += a * w.z; acc.w += a * w.w;
    }
    *reinterpret_cast<float4*>(H + (rowBase + r) * DIM + c) = acc;
}

// ---------------------------------------------------------------- agg[dst] += h[src]   (32 lanes / edge)
__global__ void scatter_add(const float* __restrict__ H, const int* __restrict__ src,
                            const int* __restrict__ dst, float* __restrict__ agg) {
    const long t = (long)blockIdx.x * blockDim.x + threadIdx.x;
    const int e = (int)(t >> 5);
    const int lane = (int)(t & 31);
    if (e >= N_EDGES) return;
    const int s = src[e];
    const int d = dst[e];
    const float4 v = *reinterpret_cast<const float4*>(H + (long)s * DIM + lane * 4);
    float* o = agg + (long)d * DIM + lane * 4;
    unsafeAtomicAdd(o + 0, v.x);
    unsafeAtomicAdd(o + 1, v.y);
    unsafeAtomicAdd(o + 2, v.z);
    unsafeAtomicAdd(o + 3, v.w);
}

// ---------------------------------------------------------------- h = relu(agg@Wgc+bgc) + relu(h@Wres+bres)
__global__ void layer_mm(const float* __restrict__ agg, float* __restrict__ H,
                         const float* __restrict__ Wgc, const float* __restrict__ bgc,
                         const float* __restrict__ Wres, const float* __restrict__ bres) {
    __shared__ float sA[8][DIM];
    __shared__ float sH[8][DIM];
    const int tid = threadIdx.x;
    const long rowBase = (long)blockIdx.x * 8;
    const int r = tid >> 5;
    const int c = (tid & 31) * 4;

    *reinterpret_cast<float4*>(&sA[r][c]) =
        *reinterpret_cast<const float4*>(agg + (rowBase + r) * DIM + c);
    *reinterpret_cast<float4*>(&sH[r][c]) =
        *reinterpret_cast<const float4*>(H + (rowBase + r) * DIM + c);
    __syncthreads();

    float4 a1 = make_float4(0.f, 0.f, 0.f, 0.f);
    float4 a2 = make_float4(0.f, 0.f, 0.f, 0.f);
    #pragma unroll 8
    for (int k = 0; k < DIM; ++k) {
        const float av = sA[r][k];
        const float hv = sH[r][k];
        const float4 wg = *reinterpret_cast<const float4*>(Wgc + k * DIM + c);
        const float4 wr = *reinterpret_cast<const float4*>(Wres + k * DIM + c);
        a1.x += av * wg.x; a1.y += av * wg.y; a1.z += av * wg.z; a1.w += av * wg.w;
        a2.x += hv * wr.x; a2.y += hv * wr.y; a2.z += hv * wr.z; a2.w += hv * wr.w;
    }

    const float4 bg = *reinterpret_cast<const float4*>(bgc + c);
    const float4 br = *reinterpret_cast<const float4*>(bres + c);
    float4 o;
    o.x = fmaxf(a1.x + bg.x, 0.f) + fmaxf(a2.x + br.x, 0.f);
    o.y = fmaxf(a1.y + bg.y, 0.f) + fmaxf(a2.y + br.y, 0.f);
    o.z = fmaxf(a1.z + bg.z, 0.f) + fmaxf(a2.z + br.z, 0.f);
    o.w = fmaxf(a1.w + bg.w, 0.f) + fmaxf(a2.w + br.w, 0.f);
    *reinterpret_cast<float4*>(H + (rowBase + r) * DIM + c) = o;
}

// ---------------------------------------------------------------- launch
extern "C" void kernel_launch(void* const* d_in, const int* in_sizes, int n_in,
                              void* d_out, int out_size, void* d_ws, size_t ws_size,
                              hipStream_t stream) {
    const float* node_feats = (const float*)d_in[0];
    const int*   src        = (const int*)d_in[1];
    const int*   dst        = (const int*)d_in[2];
    const float* W_init     = (const float*)d_in[3];
    const float* W_gc       = (const float*)d_in[4];
    const float* b_gc       = (const float*)d_in[5];
    const float* W_res      = (const float*)d_in[6];
    const float* b_res      = (const float*)d_in[7];

    float* H   = (float*)d_out;   // h lives in d_out across all layers (in-place safe: row-local update)
    float* agg = (float*)d_ws;    // 296960*128*4 = 152 MB scratch

    const int n4 = N_NODES * DIM / 4;              // 9,502,720 float4
    const int zeroGrid    = (n4 + 255) / 256;      // 37,120
    const int mmGrid      = N_NODES / 8;           // 37,120
    const int scatterGrid = (N_EDGES * 32) / 256;  // 296,960

    init_mm<<<mmGrid, 256, 0, stream>>>(node_feats, W_init, H);

    for (int l = 0; l < N_LAYERS; ++l) {
        zero_f4<<<zeroGrid, 256, 0, stream>>>((float4*)agg, n4);
        scatter_add<<<scatterGrid, 256, 0, stream>>>(H, src, dst, agg);
        layer_mm<<<mmGrid, 256, 0, stream>>>(agg, H,
                                             W_gc + (size_t)l * DIM * DIM,
                                             b_gc + (size_t)l * DIM,
                                             W_res + (size_t)l * DIM * DIM,
                                             b_res + (size_t)l * DIM);
    }
}

// Round 2
// 2263.967 us; speedup vs baseline: 6.9999x; 6.9999x over previous
//
#include <hip/hip_runtime.h>

#define N_NODES 296960
#define N_EDGES 2375680
#define IN_FEATS 75
#define DIM 128
#define N_LAYERS 3
#define SCAN_BLOCKS (N_NODES / 256)      // 1160
#define EDGE_BLOCKS (N_EDGES / 256)      // 9280 (exact)

static_assert(N_NODES % 256 == 0, "node count divisible by 256");
static_assert(N_EDGES % 256 == 0, "edge count divisible by 256");

// ================================================================ CSR build
__global__ void zero_i(int* __restrict__ p, int n) {
    int i = blockIdx.x * blockDim.x + threadIdx.x;
    if (i < n) p[i] = 0;
}

__global__ void hist_k(const int* __restrict__ dst, int* __restrict__ deg) {
    int e = blockIdx.x * 256 + threadIdx.x;
    atomicAdd(&deg[dst[e]], 1);
}

// per-256-chunk inclusive scan -> inc[], chunk totals -> bs[]
__global__ void scanA(const int* __restrict__ deg, int* __restrict__ inc,
                      int* __restrict__ bs) {
    __shared__ int lds[256];
    const int tid = threadIdx.x;
    const int i = blockIdx.x * 256 + tid;
    const int v = deg[i];
    lds[tid] = v;
    __syncthreads();
    for (int s = 1; s < 256; s <<= 1) {
        int t = (tid >= s) ? lds[tid - s] : 0;
        __syncthreads();
        lds[tid] += t;
        __syncthreads();
    }
    inc[i] = lds[tid];
    if (tid == 255) bs[blockIdx.x] = lds[255];
}

// single-block exclusive scan of bs[] in place
__global__ void scanB(int* __restrict__ bs, int nb) {
    __shared__ int lds[256];
    __shared__ int carry;
    const int tid = threadIdx.x;
    if (tid == 0) carry = 0;
    __syncthreads();
    for (int base = 0; base < nb; base += 256) {
        const int idx = base + tid;
        const int v = (idx < nb) ? bs[idx] : 0;
        lds[tid] = v;
        __syncthreads();
        for (int s = 1; s < 256; s <<= 1) {
            int t = (tid >= s) ? lds[tid - s] : 0;
            __syncthreads();
            lds[tid] += t;
            __syncthreads();
        }
        const int inc = lds[tid];
        const int c = carry;
        __syncthreads();
        if (idx < nb) bs[idx] = c + inc - v;      // exclusive
        if (tid == 255) carry = c + lds[255];
        __syncthreads();
    }
}

// rowptr[i] = inc[i] - deg[i] + bs[block]  (exclusive); also cursor copy
__global__ void scanC(const int* __restrict__ deg, int* __restrict__ rowptr,
                      const int* __restrict__ bs, int* __restrict__ cursor) {
    const int i = blockIdx.x * 256 + threadIdx.x;
    const int exc = rowptr[i] - deg[i] + bs[blockIdx.x];
    rowptr[i] = exc;
    cursor[i] = exc;
    if (i == 0) rowptr[N_NODES] = N_EDGES;
}

__global__ void fill_k(const int* __restrict__ src, const int* __restrict__ dst,
                       int* __restrict__ cursor, int* __restrict__ eidx) {
    int e = blockIdx.x * 256 + threadIdx.x;
    int p = atomicAdd(&cursor[dst[e]], 1);
    eidx[p] = src[e];
}

// ================================================================ h = X @ W_init
__global__ void init_mm(const float* __restrict__ X, const float* __restrict__ W,
                        float* __restrict__ H) {
    __shared__ float sF[8 * IN_FEATS];
    const int tid = threadIdx.x;
    const long rowBase = (long)blockIdx.x * 8;

    for (int i = tid; i < 8 * IN_FEATS; i += 256)
        sF[i] = X[rowBase * IN_FEATS + i];
    __syncthreads();

    const int r = tid >> 5;
    const int c = (tid & 31) * 4;
    float4 acc = make_float4(0.f, 0.f, 0.f, 0.f);
    for (int k = 0; k < IN_FEATS; ++k) {
        const float a = sF[r * IN_FEATS + k];
        const float4 w = *reinterpret_cast<const float4*>(W + k * DIM + c);
        acc.x += a * w.x; acc.y += a * w.y; acc.z += a * w.z; acc.w += a * w.w;
    }
    *reinterpret_cast<float4*>(H + (rowBase + r) * DIM + c) = acc;
}

// ================================================================ fused gather + dual GEMM
// Hout[n] = relu(sum_{e in CSR[n]} Hin[eidx[e]] @ Wgc + bgc) + relu(Hin[n] @ Wres + bres)
__global__ __launch_bounds__(256) void layer_fused(
    const float* __restrict__ Hin, float* __restrict__ Hout,
    const int* __restrict__ rowptr, const int* __restrict__ eidx,
    const float* __restrict__ Wgc, const float* __restrict__ bgc,
    const float* __restrict__ Wres, const float* __restrict__ bres) {
    __shared__ float sA[32][DIM];
    __shared__ float sH[32][DIM];
    const int tid = threadIdx.x;
    const int g = tid >> 5;          // 8 groups of 32 lanes
    const int lane = tid & 31;
    const long rowBase = (long)blockIdx.x * 32;

    // ---- gather phase: each 32-lane group accumulates 4 nodes ----
    for (int nn = g; nn < 32; nn += 8) {
        const int node = (int)rowBase + nn;
        const int beg = rowptr[node];
        const int end = rowptr[node + 1];
        float4 acc = make_float4(0.f, 0.f, 0.f, 0.f);
        for (int e = beg; e < end; ++e) {
            const int s = eidx[e];
            const float4 v = *reinterpret_cast<const float4*>(Hin + (long)s * DIM + lane * 4);
            acc.x += v.x; acc.y += v.y; acc.z += v.z; acc.w += v.w;
        }
        *reinterpret_cast<float4*>(&sA[nn][lane * 4]) = acc;
        *reinterpret_cast<float4*>(&sH[nn][lane * 4]) =
            *reinterpret_cast<const float4*>(Hin + ((long)node) * DIM + lane * 4);
    }
    __syncthreads();

    // ---- dual GEMM: 4 rows x 4 cols per thread ----
    const int r0 = g * 4;
    const int c = lane * 4;
    float4 a1[4], a2[4];
    #pragma unroll
    for (int rr = 0; rr < 4; ++rr) {
        a1[rr] = make_float4(0.f, 0.f, 0.f, 0.f);
        a2[rr] = make_float4(0.f, 0.f, 0.f, 0.f);
    }

    for (int k0 = 0; k0 < DIM; k0 += 4) {
        float4 av[4], hv[4];
        #pragma unroll
        for (int rr = 0; rr < 4; ++rr) {
            av[rr] = *reinterpret_cast<const float4*>(&sA[r0 + rr][k0]);
            hv[rr] = *reinterpret_cast<const float4*>(&sH[r0 + rr][k0]);
        }
        #pragma unroll
        for (int kk = 0; kk < 4; ++kk) {
            const float4 wg = *reinterpret_cast<const float4*>(Wgc + (k0 + kk) * DIM + c);
            const float4 wr = *reinterpret_cast<const float4*>(Wres + (k0 + kk) * DIM + c);
            #pragma unroll
            for (int rr = 0; rr < 4; ++rr) {
                const float a = (&av[rr].x)[kk];
                const float h = (&hv[rr].x)[kk];
                a1[rr].x += a * wg.x; a1[rr].y += a * wg.y; a1[rr].z += a * wg.z; a1[rr].w += a * wg.w;
                a2[rr].x += h * wr.x; a2[rr].y += h * wr.y; a2[rr].z += h * wr.z; a2[rr].w += h * wr.w;
            }
        }
    }

    const float4 bg = *reinterpret_cast<const float4*>(bgc + c);
    const float4 br = *reinterpret_cast<const float4*>(bres + c);
    #pragma unroll
    for (int rr = 0; rr < 4; ++rr) {
        float4 o;
        o.x = fmaxf(a1[rr].x + bg.x, 0.f) + fmaxf(a2[rr].x + br.x, 0.f);
        o.y = fmaxf(a1[rr].y + bg.y, 0.f) + fmaxf(a2[rr].y + br.y, 0.f);
        o.z = fmaxf(a1[rr].z + bg.z, 0.f) + fmaxf(a2[rr].z + br.z, 0.f);
        o.w = fmaxf(a1[rr].w + bg.w, 0.f) + fmaxf(a2[rr].w + br.w, 0.f);
        *reinterpret_cast<float4*>(Hout + (rowBase + r0 + rr) * DIM + c) = o;
    }
}

// ================================================================ fallback (round-0 path)
__global__ void zero_f4(float4* __restrict__ p, int n4) {
    int i = blockIdx.x * blockDim.x + threadIdx.x;
    if (i < n4) p[i] = make_float4(0.f, 0.f, 0.f, 0.f);
}

__global__ void scatter_add(const float* __restrict__ H, const int* __restrict__ src,
                            const int* __restrict__ dst, float* __restrict__ agg) {
    const long t = (long)blockIdx.x * blockDim.x + threadIdx.x;
    const int e = (int)(t >> 5);
    const int lane = (int)(t & 31);
    if (e >= N_EDGES) return;
    const int s = src[e];
    const int d = dst[e];
    const float4 v = *reinterpret_cast<const float4*>(H + (long)s * DIM + lane * 4);
    float* o = agg + (long)d * DIM + lane * 4;
    unsafeAtomicAdd(o + 0, v.x);
    unsafeAtomicAdd(o + 1, v.y);
    unsafeAtomicAdd(o + 2, v.z);
    unsafeAtomicAdd(o + 3, v.w);
}

__global__ void layer_mm(const float* __restrict__ agg, float* __restrict__ H,
                         const float* __restrict__ Wgc, const float* __restrict__ bgc,
                         const float* __restrict__ Wres, const float* __restrict__ bres) {
    __shared__ float sA[8][DIM];
    __shared__ float sH[8][DIM];
    const int tid = threadIdx.x;
    const long rowBase = (long)blockIdx.x * 8;
    const int r = tid >> 5;
    const int c = (tid & 31) * 4;

    *reinterpret_cast<float4*>(&sA[r][c]) =
        *reinterpret_cast<const float4*>(agg + (rowBase + r) * DIM + c);
    *reinterpret_cast<float4*>(&sH[r][c]) =
        *reinterpret_cast<const float4*>(H + (rowBase + r) * DIM + c);
    __syncthreads();

    float4 a1 = make_float4(0.f, 0.f, 0.f, 0.f);
    float4 a2 = make_float4(0.f, 0.f, 0.f, 0.f);
    #pragma unroll 8
    for (int k = 0; k < DIM; ++k) {
        const float av = sA[r][k];
        const float hv = sH[r][k];
        const float4 wg = *reinterpret_cast<const float4*>(Wgc + k * DIM + c);
        const float4 wr = *reinterpret_cast<const float4*>(Wres + k * DIM + c);
        a1.x += av * wg.x; a1.y += av * wg.y; a1.z += av * wg.z; a1.w += av * wg.w;
        a2.x += hv * wr.x; a2.y += hv * wr.y; a2.z += hv * wr.z; a2.w += hv * wr.w;
    }

    const float4 bg = *reinterpret_cast<const float4*>(bgc + c);
    const float4 br = *reinterpret_cast<const float4*>(bres + c);
    float4 o;
    o.x = fmaxf(a1.x + bg.x, 0.f) + fmaxf(a2.x + br.x, 0.f);
    o.y = fmaxf(a1.y + bg.y, 0.f) + fmaxf(a2.y + br.y, 0.f);
    o.z = fmaxf(a1.z + bg.z, 0.f) + fmaxf(a2.z + br.z, 0.f);
    o.w = fmaxf(a1.w + bg.w, 0.f) + fmaxf(a2.w + br.w, 0.f);
    *reinterpret_cast<float4*>(H + (rowBase + r) * DIM + c) = o;
}

// ================================================================ launch
extern "C" void kernel_launch(void* const* d_in, const int* in_sizes, int n_in,
                              void* d_out, int out_size, void* d_ws, size_t ws_size,
                              hipStream_t stream) {
    const float* node_feats = (const float*)d_in[0];
    const int*   src        = (const int*)d_in[1];
    const int*   dst        = (const int*)d_in[2];
    const float* W_init     = (const float*)d_in[3];
    const float* W_gc       = (const float*)d_in[4];
    const float* b_gc       = (const float*)d_in[5];
    const float* W_res      = (const float*)d_in[6];
    const float* b_res      = (const float*)d_in[7];

    // ---- ws layout (all offsets in bytes, 256-aligned) ----
    const size_t H_BYTES   = (size_t)N_NODES * DIM * sizeof(float);    // 152,043,520
    const size_t RP_BYTES  = ((size_t)(N_NODES + 1) * 4 + 255) & ~255ull;
    const size_t DEG_BYTES = ((size_t)N_NODES * 4 + 255) & ~255ull;
    const size_t CUR_BYTES = DEG_BYTES;
    const size_t BS_BYTES  = ((size_t)SCAN_BLOCKS * 4 + 255) & ~255ull;
    const size_t EIDX_BYTES = (size_t)N_EDGES * 4;
    const size_t NEED = H_BYTES + RP_BYTES + DEG_BYTES + CUR_BYTES + BS_BYTES + EIDX_BYTES;

    if (ws_size >= NEED) {
        char* w = (char*)d_ws;
        float* Ha     = (float*)w;                    w += H_BYTES;
        int*   rowptr = (int*)w;                      w += RP_BYTES;
        int*   deg    = (int*)w;                      w += DEG_BYTES;
        int*   cursor = (int*)w;                      w += CUR_BYTES;
        int*   bs     = (int*)w;                      w += BS_BYTES;
        int*   eidx   = (int*)w;
        float* Hb     = (float*)d_out;

        // CSR build (reused by all 3 layers)
        zero_i<<<SCAN_BLOCKS, 256, 0, stream>>>(deg, N_NODES);
        hist_k<<<EDGE_BLOCKS, 256, 0, stream>>>(dst, deg);
        scanA<<<SCAN_BLOCKS, 256, 0, stream>>>(deg, rowptr, bs);
        scanB<<<1, 256, 0, stream>>>(bs, SCAN_BLOCKS);
        scanC<<<SCAN_BLOCKS, 256, 0, stream>>>(deg, rowptr, bs, cursor);
        fill_k<<<EDGE_BLOCKS, 256, 0, stream>>>(src, dst, cursor, eidx);

        // h0 -> Ha
        init_mm<<<N_NODES / 8, 256, 0, stream>>>(node_feats, W_init, Ha);

        // L0: Ha -> Hb(d_out); L1: Hb -> Ha; L2: Ha -> Hb(d_out)
        const float* in_ptrs[3]  = {Ha, Hb, Ha};
        float*       out_ptrs[3] = {Hb, Ha, Hb};
        for (int l = 0; l < N_LAYERS; ++l) {
            layer_fused<<<N_NODES / 32, 256, 0, stream>>>(
                in_ptrs[l], out_ptrs[l], rowptr, eidx,
                W_gc + (size_t)l * DIM * DIM, b_gc + (size_t)l * DIM,
                W_res + (size_t)l * DIM * DIM, b_res + (size_t)l * DIM);
        }
    } else {
        // fallback: round-0 atomic-scatter path (needs only H_BYTES of ws)
        float* H   = (float*)d_out;
        float* agg = (float*)d_ws;
        const int n4 = N_NODES * DIM / 4;
        init_mm<<<N_NODES / 8, 256, 0, stream>>>(node_feats, W_init, H);
        for (int l = 0; l < N_LAYERS; ++l) {
            zero_f4<<<(n4 + 255) / 256, 256, 0, stream>>>((float4*)agg, n4);
            scatter_add<<<(N_EDGES * 32) / 256, 256, 0, stream>>>(H, src, dst, agg);
            layer_mm<<<N_NODES / 8, 256, 0, stream>>>(agg, H,
                W_gc + (size_t)l * DIM * DIM, b_gc + (size_t)l * DIM,
                W_res + (size_t)l * DIM * DIM, b_res + (size_t)l * DIM);
        }
    }
}

// Round 3
// 2003.505 us; speedup vs baseline: 7.9099x; 1.1300x over previous
//
#include <hip/hip_runtime.h>

#define N_NODES 296960
#define N_EDGES 2375680
#define IN_FEATS 75
#define DIM 128
#define N_LAYERS 3
#define SCAN_BLOCKS (N_NODES / 256)      // 1160
#define EDGE_BLOCKS (N_EDGES / 256)      // 9280 (exact)
#define ECAP 2048                        // staged edge indices per block (8 KB, aliases sA)

static_assert(N_NODES % 256 == 0, "node count divisible by 256");
static_assert(N_EDGES % 256 == 0, "edge count divisible by 256");

// ================================================================ CSR build
__global__ void zero_i(int* __restrict__ p, int n) {
    int i = blockIdx.x * blockDim.x + threadIdx.x;
    if (i < n) p[i] = 0;
}

__global__ void hist_k(const int* __restrict__ dst, int* __restrict__ deg) {
    int e = blockIdx.x * 256 + threadIdx.x;
    atomicAdd(&deg[dst[e]], 1);
}

__global__ void scanA(const int* __restrict__ deg, int* __restrict__ inc,
                      int* __restrict__ bs) {
    __shared__ int lds[256];
    const int tid = threadIdx.x;
    const int i = blockIdx.x * 256 + tid;
    const int v = deg[i];
    lds[tid] = v;
    __syncthreads();
    for (int s = 1; s < 256; s <<= 1) {
        int t = (tid >= s) ? lds[tid - s] : 0;
        __syncthreads();
        lds[tid] += t;
        __syncthreads();
    }
    inc[i] = lds[tid];
    if (tid == 255) bs[blockIdx.x] = lds[255];
}

__global__ void scanB(int* __restrict__ bs, int nb) {
    __shared__ int lds[256];
    __shared__ int carry;
    const int tid = threadIdx.x;
    if (tid == 0) carry = 0;
    __syncthreads();
    for (int base = 0; base < nb; base += 256) {
        const int idx = base + tid;
        const int v = (idx < nb) ? bs[idx] : 0;
        lds[tid] = v;
        __syncthreads();
        for (int s = 1; s < 256; s <<= 1) {
            int t = (tid >= s) ? lds[tid - s] : 0;
            __syncthreads();
            lds[tid] += t;
            __syncthreads();
        }
        const int inc = lds[tid];
        const int c = carry;
        __syncthreads();
        if (idx < nb) bs[idx] = c + inc - v;
        if (tid == 255) carry = c + lds[255];
        __syncthreads();
    }
}

__global__ void scanC(const int* __restrict__ deg, int* __restrict__ rowptr,
                      const int* __restrict__ bs, int* __restrict__ cursor) {
    const int i = blockIdx.x * 256 + threadIdx.x;
    const int exc = rowptr[i] - deg[i] + bs[blockIdx.x];
    rowptr[i] = exc;
    cursor[i] = exc;
    if (i == 0) rowptr[N_NODES] = N_EDGES;
}

__global__ void fill_k(const int* __restrict__ src, const int* __restrict__ dst,
                       int* __restrict__ cursor, int* __restrict__ eidx) {
    int e = blockIdx.x * 256 + threadIdx.x;
    int p = atomicAdd(&cursor[dst[e]], 1);
    eidx[p] = src[e];
}

// ================================================================ h = X @ W_init
__global__ void init_mm(const float* __restrict__ X, const float* __restrict__ W,
                        float* __restrict__ H) {
    __shared__ float sF[8 * IN_FEATS];
    const int tid = threadIdx.x;
    const long rowBase = (long)blockIdx.x * 8;

    for (int i = tid; i < 8 * IN_FEATS; i += 256)
        sF[i] = X[rowBase * IN_FEATS + i];
    __syncthreads();

    const int r = tid >> 5;
    const int c = (tid & 31) * 4;
    float4 acc = make_float4(0.f, 0.f, 0.f, 0.f);
    for (int k = 0; k < IN_FEATS; ++k) {
        const float a = sF[r * IN_FEATS + k];
        const float4 w = *reinterpret_cast<const float4*>(W + k * DIM + c);
        acc.x += a * w.x; acc.y += a * w.y; acc.z += a * w.z; acc.w += a * w.w;
    }
    *reinterpret_cast<float4*>(H + (rowBase + r) * DIM + c) = acc;
}

// ================================================================ fused gather + dual GEMM
// Hout[n] = relu(sum_{e in CSR[n]} Hin[eidx[e]] @ Wgc + bgc) + relu(Hin[n] @ Wres + bres)
__global__ __launch_bounds__(256) void layer_fused(
    const float* __restrict__ Hin, float* __restrict__ Hout,
    const int* __restrict__ rowptr, const int* __restrict__ eidx,
    const float* __restrict__ Wgc, const float* __restrict__ bgc,
    const float* __restrict__ Wres, const float* __restrict__ bres) {
    __shared__ float sA[32][DIM];   // 16 KB (first 8 KB alias sE during staging)
    __shared__ float sH[32][DIM];   // 16 KB
    int* sE = (int*)&sA[0][0];

    const int tid = threadIdx.x;
    const int g = tid >> 5;          // 8 groups of 32 lanes
    const int lane = tid & 31;
    const int rowBase = blockIdx.x * 32;

    const int blkBeg = rowptr[rowBase];
    const int blkEnd = rowptr[rowBase + 32];
    const int nE = blkEnd - blkBeg;
    const int nStage = (nE < ECAP) ? nE : ECAP;

    // ---- stage edge indices into LDS (coalesced; breaks the eidx->H dependent chain) ----
    for (int i = tid; i < nStage; i += 256)
        sE[i] = eidx[blkBeg + i];
    __syncthreads();

    // ---- gather into registers: group g handles nodes g, g+8, g+16, g+24 ----
    float4 accs[4];
    float4 own[4];
    #pragma unroll
    for (int ii = 0; ii < 4; ++ii) {
        const int node = rowBase + g + ii * 8;
        const int beg = rowptr[node];
        const int end = rowptr[node + 1];
        own[ii] = *reinterpret_cast<const float4*>(Hin + (long)node * DIM + lane * 4);
        float4 a0 = make_float4(0.f, 0.f, 0.f, 0.f);
        float4 a1 = make_float4(0.f, 0.f, 0.f, 0.f);
        int e = beg;
        for (; e + 2 <= end; e += 2) {
            const int o0 = e - blkBeg;
            const int o1 = o0 + 1;
            const int s0 = (o0 < ECAP) ? sE[o0] : eidx[e];
            const int s1 = (o1 < ECAP) ? sE[o1] : eidx[e + 1];
            const float4 v0 = *reinterpret_cast<const float4*>(Hin + (long)s0 * DIM + lane * 4);
            const float4 v1 = *reinterpret_cast<const float4*>(Hin + (long)s1 * DIM + lane * 4);
            a0.x += v0.x; a0.y += v0.y; a0.z += v0.z; a0.w += v0.w;
            a1.x += v1.x; a1.y += v1.y; a1.z += v1.z; a1.w += v1.w;
        }
        if (e < end) {
            const int o = e - blkBeg;
            const int s = (o < ECAP) ? sE[o] : eidx[e];
            const float4 v = *reinterpret_cast<const float4*>(Hin + (long)s * DIM + lane * 4);
            a0.x += v.x; a0.y += v.y; a0.z += v.z; a0.w += v.w;
        }
        accs[ii] = make_float4(a0.x + a1.x, a0.y + a1.y, a0.z + a1.z, a0.w + a1.w);
    }
    __syncthreads();   // all groups done reading sE before overwriting sA

    #pragma unroll
    for (int ii = 0; ii < 4; ++ii) {
        const int nn = g + ii * 8;
        *reinterpret_cast<float4*>(&sA[nn][lane * 4]) = accs[ii];
        *reinterpret_cast<float4*>(&sH[nn][lane * 4]) = own[ii];
    }
    __syncthreads();

    // ---- dual GEMM: 4 rows x 4 cols per thread ----
    const int r0 = g * 4;
    const int c = lane * 4;
    float4 a1[4], a2[4];
    #pragma unroll
    for (int rr = 0; rr < 4; ++rr) {
        a1[rr] = make_float4(0.f, 0.f, 0.f, 0.f);
        a2[rr] = make_float4(0.f, 0.f, 0.f, 0.f);
    }

    for (int k0 = 0; k0 < DIM; k0 += 4) {
        float4 av[4], hv[4];
        #pragma unroll
        for (int rr = 0; rr < 4; ++rr) {
            av[rr] = *reinterpret_cast<const float4*>(&sA[r0 + rr][k0]);
            hv[rr] = *reinterpret_cast<const float4*>(&sH[r0 + rr][k0]);
        }
        #pragma unroll
        for (int kk = 0; kk < 4; ++kk) {
            const float4 wg = *reinterpret_cast<const float4*>(Wgc + (k0 + kk) * DIM + c);
            const float4 wr = *reinterpret_cast<const float4*>(Wres + (k0 + kk) * DIM + c);
            #pragma unroll
            for (int rr = 0; rr < 4; ++rr) {
                const float a = (&av[rr].x)[kk];
                const float h = (&hv[rr].x)[kk];
                a1[rr].x += a * wg.x; a1[rr].y += a * wg.y; a1[rr].z += a * wg.z; a1[rr].w += a * wg.w;
                a2[rr].x += h * wr.x; a2[rr].y += h * wr.y; a2[rr].z += h * wr.z; a2[rr].w += h * wr.w;
            }
        }
    }

    const float4 bg = *reinterpret_cast<const float4*>(bgc + c);
    const float4 br = *reinterpret_cast<const float4*>(bres + c);
    #pragma unroll
    for (int rr = 0; rr < 4; ++rr) {
        float4 o;
        o.x = fmaxf(a1[rr].x + bg.x, 0.f) + fmaxf(a2[rr].x + br.x, 0.f);
        o.y = fmaxf(a1[rr].y + bg.y, 0.f) + fmaxf(a2[rr].y + br.y, 0.f);
        o.z = fmaxf(a1[rr].z + bg.z, 0.f) + fmaxf(a2[rr].z + br.z, 0.f);
        o.w = fmaxf(a1[rr].w + bg.w, 0.f) + fmaxf(a2[rr].w + br.w, 0.f);
        *reinterpret_cast<float4*>(Hout + (long)(rowBase + r0 + rr) * DIM + c) = o;
    }
}

// ================================================================ fallback (round-0 path)
__global__ void zero_f4(float4* __restrict__ p, int n4) {
    int i = blockIdx.x * blockDim.x + threadIdx.x;
    if (i < n4) p[i] = make_float4(0.f, 0.f, 0.f, 0.f);
}

__global__ void scatter_add(const float* __restrict__ H, const int* __restrict__ src,
                            const int* __restrict__ dst, float* __restrict__ agg) {
    const long t = (long)blockIdx.x * blockDim.x + threadIdx.x;
    const int e = (int)(t >> 5);
    const int lane = (int)(t & 31);
    if (e >= N_EDGES) return;
    const int s = src[e];
    const int d = dst[e];
    const float4 v = *reinterpret_cast<const float4*>(H + (long)s * DIM + lane * 4);
    float* o = agg + (long)d * DIM + lane * 4;
    unsafeAtomicAdd(o + 0, v.x);
    unsafeAtomicAdd(o + 1, v.y);
    unsafeAtomicAdd(o + 2, v.z);
    unsafeAtomicAdd(o + 3, v.w);
}

__global__ void layer_mm(const float* __restrict__ agg, float* __restrict__ H,
                         const float* __restrict__ Wgc, const float* __restrict__ bgc,
                         const float* __restrict__ Wres, const float* __restrict__ bres) {
    __shared__ float sA[8][DIM];
    __shared__ float sH[8][DIM];
    const int tid = threadIdx.x;
    const long rowBase = (long)blockIdx.x * 8;
    const int r = tid >> 5;
    const int c = (tid & 31) * 4;

    *reinterpret_cast<float4*>(&sA[r][c]) =
        *reinterpret_cast<const float4*>(agg + (rowBase + r) * DIM + c);
    *reinterpret_cast<float4*>(&sH[r][c]) =
        *reinterpret_cast<const float4*>(H + (rowBase + r) * DIM + c);
    __syncthreads();

    float4 a1 = make_float4(0.f, 0.f, 0.f, 0.f);
    float4 a2 = make_float4(0.f, 0.f, 0.f, 0.f);
    #pragma unroll 8
    for (int k = 0; k < DIM; ++k) {
        const float av = sA[r][k];
        const float hv = sH[r][k];
        const float4 wg = *reinterpret_cast<const float4*>(Wgc + k * DIM + c);
        const float4 wr = *reinterpret_cast<const float4*>(Wres + k * DIM + c);
        a1.x += av * wg.x; a1.y += av * wg.y; a1.z += av * wg.z; a1.w += av * wg.w;
        a2.x += hv * wr.x; a2.y += hv * wr.y; a2.z += hv * wr.z; a2.w += hv * wr.w;
    }

    const float4 bg = *reinterpret_cast<const float4*>(bgc + c);
    const float4 br = *reinterpret_cast<const float4*>(bres + c);
    float4 o;
    o.x = fmaxf(a1.x + bg.x, 0.f) + fmaxf(a2.x + br.x, 0.f);
    o.y = fmaxf(a1.y + bg.y, 0.f) + fmaxf(a2.y + br.y, 0.f);
    o.z = fmaxf(a1.z + bg.z, 0.f) + fmaxf(a2.z + br.z, 0.f);
    o.w = fmaxf(a1.w + bg.w, 0.f) + fmaxf(a2.w + br.w, 0.f);
    *reinterpret_cast<float4*>(H + (rowBase + r) * DIM + c) = o;
}

// ================================================================ launch
extern "C" void kernel_launch(void* const* d_in, const int* in_sizes, int n_in,
                              void* d_out, int out_size, void* d_ws, size_t ws_size,
                              hipStream_t stream) {
    const float* node_feats = (const float*)d_in[0];
    const int*   src        = (const int*)d_in[1];
    const int*   dst        = (const int*)d_in[2];
    const float* W_init     = (const float*)d_in[3];
    const float* W_gc       = (const float*)d_in[4];
    const float* b_gc       = (const float*)d_in[5];
    const float* W_res      = (const float*)d_in[6];
    const float* b_res      = (const float*)d_in[7];

    const size_t H_BYTES   = (size_t)N_NODES * DIM * sizeof(float);
    const size_t RP_BYTES  = ((size_t)(N_NODES + 1) * 4 + 255) & ~255ull;
    const size_t DEG_BYTES = ((size_t)N_NODES * 4 + 255) & ~255ull;
    const size_t CUR_BYTES = DEG_BYTES;
    const size_t BS_BYTES  = ((size_t)SCAN_BLOCKS * 4 + 255) & ~255ull;
    const size_t EIDX_BYTES = (size_t)N_EDGES * 4;
    const size_t NEED = H_BYTES + RP_BYTES + DEG_BYTES + CUR_BYTES + BS_BYTES + EIDX_BYTES;

    if (ws_size >= NEED) {
        char* w = (char*)d_ws;
        float* Ha     = (float*)w;                    w += H_BYTES;
        int*   rowptr = (int*)w;                      w += RP_BYTES;
        int*   deg    = (int*)w;                      w += DEG_BYTES;
        int*   cursor = (int*)w;                      w += CUR_BYTES;
        int*   bs     = (int*)w;                      w += BS_BYTES;
        int*   eidx   = (int*)w;
        float* Hb     = (float*)d_out;

        zero_i<<<SCAN_BLOCKS, 256, 0, stream>>>(deg, N_NODES);
        hist_k<<<EDGE_BLOCKS, 256, 0, stream>>>(dst, deg);
        scanA<<<SCAN_BLOCKS, 256, 0, stream>>>(deg, rowptr, bs);
        scanB<<<1, 256, 0, stream>>>(bs, SCAN_BLOCKS);
        scanC<<<SCAN_BLOCKS, 256, 0, stream>>>(deg, rowptr, bs, cursor);
        fill_k<<<EDGE_BLOCKS, 256, 0, stream>>>(src, dst, cursor, eidx);

        init_mm<<<N_NODES / 8, 256, 0, stream>>>(node_feats, W_init, Ha);

        const float* in_ptrs[3]  = {Ha, Hb, Ha};
        float*       out_ptrs[3] = {Hb, Ha, Hb};
        for (int l = 0; l < N_LAYERS; ++l) {
            layer_fused<<<N_NODES / 32, 256, 0, stream>>>(
                in_ptrs[l], out_ptrs[l], rowptr, eidx,
                W_gc + (size_t)l * DIM * DIM, b_gc + (size_t)l * DIM,
                W_res + (size_t)l * DIM * DIM, b_res + (size_t)l * DIM);
        }
    } else {
        float* H   = (float*)d_out;
        float* agg = (float*)d_ws;
        const int n4 = N_NODES * DIM / 4;
        init_mm<<<N_NODES / 8, 256, 0, stream>>>(node_feats, W_init, H);
        for (int l = 0; l < N_LAYERS; ++l) {
            zero_f4<<<(n4 + 255) / 256, 256, 0, stream>>>((float4*)agg, n4);
            scatter_add<<<(N_EDGES * 32) / 256, 256, 0, stream>>>(H, src, dst, agg);
            layer_mm<<<N_NODES / 8, 256, 0, stream>>>(agg, H,
                W_gc + (size_t)l * DIM * DIM, b_gc + (size_t)l * DIM,
                W_res + (size_t)l * DIM * DIM, b_res + (size_t)l * DIM);
        }
    }
}

// Round 4
// 1182.135 us; speedup vs baseline: 13.4058x; 1.6948x over previous
//
#include <hip/hip_runtime.h>

#define N_NODES 296960
#define N_EDGES 2375680
#define IN_FEATS 75
#define DIM 128
#define N_LAYERS 3
#define SCAN_BLOCKS (N_NODES / 256)      // 1160
#define EDGE_BLOCKS (N_EDGES / 256)      // 9280
#define ECAP 4096                        // staged edge indices (16 KB, aliases both tiles)

static_assert(N_NODES % 256 == 0, "node count divisible by 256");
static_assert(N_EDGES % 256 == 0, "edge count divisible by 256");

typedef __attribute__((ext_vector_type(8))) short s8v;   // 8 bf16 = 4 VGPR MFMA frag
typedef __attribute__((ext_vector_type(4))) float f4v;   // 4 f32 accum frag

__device__ __forceinline__ float u2f(unsigned int x) {
    union { unsigned int u; float f; } v; v.u = x; return v.f;
}
__device__ __forceinline__ unsigned short f2b(float f) {   // f32 -> bf16 RNE
    union { float f; unsigned int u; } v; v.f = f;
    unsigned int r = v.u + 0x7fffu + ((v.u >> 16) & 1u);
    return (unsigned short)(r >> 16);
}
__device__ __forceinline__ void addbf(f4v& a, uint2 q) {   // accumulate 4 bf16 into f32x4
    a.x += u2f(q.x << 16);
    a.y += u2f(q.x & 0xffff0000u);
    a.z += u2f(q.y << 16);
    a.w += u2f(q.y & 0xffff0000u);
}

// ================================================================ CSR build
__global__ void zero_i(int* __restrict__ p, int n) {
    int i = blockIdx.x * blockDim.x + threadIdx.x;
    if (i < n) p[i] = 0;
}

__global__ void hist_k(const int* __restrict__ dst, int* __restrict__ deg) {
    int e = blockIdx.x * 256 + threadIdx.x;
    atomicAdd(&deg[dst[e]], 1);
}

__global__ void scanA(const int* __restrict__ deg, int* __restrict__ inc,
                      int* __restrict__ bs) {
    __shared__ int lds[256];
    const int tid = threadIdx.x;
    const int i = blockIdx.x * 256 + tid;
    const int v = deg[i];
    lds[tid] = v;
    __syncthreads();
    for (int s = 1; s < 256; s <<= 1) {
        int t = (tid >= s) ? lds[tid - s] : 0;
        __syncthreads();
        lds[tid] += t;
        __syncthreads();
    }
    inc[i] = lds[tid];
    if (tid == 255) bs[blockIdx.x] = lds[255];
}

__global__ void scanB(int* __restrict__ bs, int nb) {
    __shared__ int lds[256];
    __shared__ int carry;
    const int tid = threadIdx.x;
    if (tid == 0) carry = 0;
    __syncthreads();
    for (int base = 0; base < nb; base += 256) {
        const int idx = base + tid;
        const int v = (idx < nb) ? bs[idx] : 0;
        lds[tid] = v;
        __syncthreads();
        for (int s = 1; s < 256; s <<= 1) {
            int t = (tid >= s) ? lds[tid - s] : 0;
            __syncthreads();
            lds[tid] += t;
            __syncthreads();
        }
        const int inc = lds[tid];
        const int c = carry;
        __syncthreads();
        if (idx < nb) bs[idx] = c + inc - v;
        if (tid == 255) carry = c + lds[255];
        __syncthreads();
    }
}

__global__ void scanC(const int* __restrict__ deg, int* __restrict__ rowptr,
                      const int* __restrict__ bs, int* __restrict__ cursor) {
    const int i = blockIdx.x * 256 + threadIdx.x;
    const int exc = rowptr[i] - deg[i] + bs[blockIdx.x];
    rowptr[i] = exc;
    cursor[i] = exc;
    if (i == 0) rowptr[N_NODES] = N_EDGES;
}

__global__ void fill_k(const int* __restrict__ src, const int* __restrict__ dst,
                       int* __restrict__ cursor, int* __restrict__ eidx) {
    int e = blockIdx.x * 256 + threadIdx.x;
    int p = atomicAdd(&cursor[dst[e]], 1);
    eidx[p] = src[e];
}

// ================================================================ weight transpose+cvt: Wt[m][n][k] = bf16(W_m[k][n])
__global__ void wcvt(const float* __restrict__ Wgc, const float* __restrict__ Wres,
                     unsigned short* __restrict__ Wt) {
    const int m = blockIdx.x >> 6;                       // 6 mats x 64 blocks
    const int idx = (blockIdx.x & 63) * 256 + threadIdx.x;  // 0..16383
    const float* src = (m < 3) ? (Wgc + m * 16384) : (Wres + (m - 3) * 16384);
    const int n = idx >> 7, k = idx & 127;
    Wt[m * 16384 + idx] = f2b(src[k * 128 + n]);
}

// ================================================================ h0 = X @ W_init  -> bf16
__global__ void init_mm_bf(const float* __restrict__ X, const float* __restrict__ W,
                           unsigned short* __restrict__ H) {
    __shared__ float sF[8 * IN_FEATS];
    const int tid = threadIdx.x;
    const long rowBase = (long)blockIdx.x * 8;

    for (int i = tid; i < 8 * IN_FEATS; i += 256)
        sF[i] = X[rowBase * IN_FEATS + i];
    __syncthreads();

    const int r = tid >> 5;
    const int c = (tid & 31) * 4;
    float4 acc = make_float4(0.f, 0.f, 0.f, 0.f);
    for (int k = 0; k < IN_FEATS; ++k) {
        const float a = sF[r * IN_FEATS + k];
        const float4 w = *reinterpret_cast<const float4*>(W + k * DIM + c);
        acc.x += a * w.x; acc.y += a * w.y; acc.z += a * w.z; acc.w += a * w.w;
    }
    uint2 p;
    p.x = (unsigned)f2b(acc.x) | ((unsigned)f2b(acc.y) << 16);
    p.y = (unsigned)f2b(acc.z) | ((unsigned)f2b(acc.w) << 16);
    *reinterpret_cast<uint2*>(H + (rowBase + r) * DIM + c) = p;
}

// ================================================================ fused gather + dual MFMA GEMM
// Hout[n] = relu(sum_nbr Hin[nbr] @ Wgc + bgc) + relu(Hin[n] @ Wres + bres)
// 32 nodes/block, 256 threads (4 waves). A-tiles bf16 in LDS, XOR-swizzled.
template <int LAST>
__global__ __launch_bounds__(256) void layer_mfma(
    const unsigned short* __restrict__ Hin, unsigned short* __restrict__ HoutB,
    float* __restrict__ HoutF,
    const int* __restrict__ rowptr, const int* __restrict__ eidx,
    const unsigned short* __restrict__ WgcT, const unsigned short* __restrict__ WresT,
    const float* __restrict__ bgc, const float* __restrict__ bres) {
    __shared__ short sTiles[2][32][DIM];     // [0]=agg, [1]=own : 16 KB total
    int* sE = (int*)&sTiles[0][0][0];        // aliases both tiles during staging (4096 ints)
    char* aggB = (char*)&sTiles[0][0][0];
    char* ownB = (char*)&sTiles[1][0][0];

    const int tid = threadIdx.x;
    const int rowBase = blockIdx.x * 32;

    const int blkBeg = rowptr[rowBase];
    const int blkEnd = rowptr[rowBase + 32];
    const int nE = blkEnd - blkBeg;
    const int nStage = (nE < ECAP) ? nE : ECAP;

    // ---- stage edge indices (coalesced; kills the eidx->H dependent chain) ----
    for (int i = tid; i < nStage; i += 256)
        sE[i] = eidx[blkBeg + i];
    __syncthreads();

    // ---- gather: group g (32 lanes) handles nodes g*4..g*4+3; lane = 4 channels ----
    const int g = tid >> 5;
    const int lane = tid & 31;
    f4v accs[4];
    uint2 own[4];
    #pragma unroll
    for (int ii = 0; ii < 4; ++ii) {
        const int node = rowBase + g * 4 + ii;
        const int beg = rowptr[node];
        const int end = rowptr[node + 1];
        own[ii] = *reinterpret_cast<const uint2*>(Hin + (size_t)node * DIM + lane * 4);
        f4v a0 = {0.f, 0.f, 0.f, 0.f};
        f4v a1 = {0.f, 0.f, 0.f, 0.f};
        int e = beg;
        for (; e + 2 <= end; e += 2) {
            const int o0 = e - blkBeg, o1 = o0 + 1;
            const int s0 = (o0 < ECAP) ? sE[o0] : eidx[e];
            const int s1 = (o1 < ECAP) ? sE[o1] : eidx[e + 1];
            const uint2 q0 = *reinterpret_cast<const uint2*>(Hin + (size_t)s0 * DIM + lane * 4);
            const uint2 q1 = *reinterpret_cast<const uint2*>(Hin + (size_t)s1 * DIM + lane * 4);
            addbf(a0, q0);
            addbf(a1, q1);
        }
        if (e < end) {
            const int o = e - blkBeg;
            const int s = (o < ECAP) ? sE[o] : eidx[e];
            addbf(a0, *reinterpret_cast<const uint2*>(Hin + (size_t)s * DIM + lane * 4));
        }
        accs[ii] = a0 + a1;
    }
    __syncthreads();   // sE dead

    // ---- write swizzled bf16 A-tiles:  byte = row*256 + (kbyte ^ ((row&7)<<4)) ----
    #pragma unroll
    for (int ii = 0; ii < 4; ++ii) {
        const int row = g * 4 + ii;
        const int kbyte = lane * 8;
        const int sw = kbyte ^ ((row & 7) << 4);
        uint2 p;
        p.x = (unsigned)f2b(accs[ii].x) | ((unsigned)f2b(accs[ii].y) << 16);
        p.y = (unsigned)f2b(accs[ii].z) | ((unsigned)f2b(accs[ii].w) << 16);
        *reinterpret_cast<uint2*>(aggB + row * 256 + sw) = p;
        *reinterpret_cast<uint2*>(ownB + row * 256 + sw) = own[ii];
    }
    __syncthreads();

    // ---- dual MFMA GEMM: wave w -> cols [w*32, w*32+32), rows 0..31 ----
    const int w = tid >> 6;
    const int l = tid & 63;
    const int lr = l & 15;      // row (A) / col (B,D) within 16-tile
    const int lk = l >> 4;      // k-group 0..3

    f4v accG[2][2] = {{{0.f,0.f,0.f,0.f},{0.f,0.f,0.f,0.f}},{{0.f,0.f,0.f,0.f},{0.f,0.f,0.f,0.f}}};
    f4v accR[2][2] = {{{0.f,0.f,0.f,0.f},{0.f,0.f,0.f,0.f}},{{0.f,0.f,0.f,0.f},{0.f,0.f,0.f,0.f}}};

    #pragma unroll
    for (int kb = 0; kb < 4; ++kb) {
        const int kofs = kb * 32 + lk * 8;   // element index, 8 contiguous k per lane
        const int kbyte = kofs * 2;
        s8v aG[2], aO[2];
        #pragma unroll
        for (int rt = 0; rt < 2; ++rt) {
            const int row = rt * 16 + lr;
            const int byte = row * 256 + (kbyte ^ ((row & 7) << 4));
            aG[rt] = *reinterpret_cast<const s8v*>(aggB + byte);
            aO[rt] = *reinterpret_cast<const s8v*>(ownB + byte);
        }
        s8v bG[2], bR[2];
        #pragma unroll
        for (int ct = 0; ct < 2; ++ct) {
            const int col = w * 32 + ct * 16 + lr;
            const size_t off = (size_t)col * DIM + kofs;   // Wt[n][k], contiguous k
            bG[ct] = *reinterpret_cast<const s8v*>(WgcT + off);
            bR[ct] = *reinterpret_cast<const s8v*>(WresT + off);
        }
        #pragma unroll
        for (int rt = 0; rt < 2; ++rt) {
            #pragma unroll
            for (int ct = 0; ct < 2; ++ct) {
                accG[rt][ct] = __builtin_amdgcn_mfma_f32_16x16x32_bf16(aG[rt], bG[ct], accG[rt][ct], 0, 0, 0);
                accR[rt][ct] = __builtin_amdgcn_mfma_f32_16x16x32_bf16(aO[rt], bR[ct], accR[rt][ct], 0, 0, 0);
            }
        }
    }

    // ---- epilogue: D col=lane&15, row=(lane>>4)*4+reg ----
    #pragma unroll
    for (int ct = 0; ct < 2; ++ct) {
        const int col = w * 32 + ct * 16 + lr;
        const float bg = bgc[col];
        const float br = bres[col];
        #pragma unroll
        for (int rt = 0; rt < 2; ++rt) {
            #pragma unroll
            for (int r = 0; r < 4; ++r) {
                const int row = rowBase + rt * 16 + lk * 4 + r;
                const float v = fmaxf(accG[rt][ct][r] + bg, 0.f) + fmaxf(accR[rt][ct][r] + br, 0.f);
                if (LAST) HoutF[(size_t)row * DIM + col] = v;
                else      HoutB[(size_t)row * DIM + col] = f2b(v);
            }
        }
    }
}

// ================================================================ fp32 fallback path (round-0 style)
__global__ void init_mm(const float* __restrict__ X, const float* __restrict__ W,
                        float* __restrict__ H) {
    __shared__ float sF[8 * IN_FEATS];
    const int tid = threadIdx.x;
    const long rowBase = (long)blockIdx.x * 8;
    for (int i = tid; i < 8 * IN_FEATS; i += 256)
        sF[i] = X[rowBase * IN_FEATS + i];
    __syncthreads();
    const int r = tid >> 5;
    const int c = (tid & 31) * 4;
    float4 acc = make_float4(0.f, 0.f, 0.f, 0.f);
    for (int k = 0; k < IN_FEATS; ++k) {
        const float a = sF[r * IN_FEATS + k];
        const float4 w = *reinterpret_cast<const float4*>(W + k * DIM + c);
        acc.x += a * w.x; acc.y += a * w.y; acc.z += a * w.z; acc.w += a * w.w;
    }
    *reinterpret_cast<float4*>(H + (rowBase + r) * DIM + c) = acc;
}

__global__ void zero_f4(float4* __restrict__ p, int n4) {
    int i = blockIdx.x * blockDim.x + threadIdx.x;
    if (i < n4) p[i] = make_float4(0.f, 0.f, 0.f, 0.f);
}

__global__ void scatter_add(const float* __restrict__ H, const int* __restrict__ src,
                            const int* __restrict__ dst, float* __restrict__ agg) {
    const long t = (long)blockIdx.x * blockDim.x + threadIdx.x;
    const int e = (int)(t >> 5);
    const int lane = (int)(t & 31);
    if (e >= N_EDGES) return;
    const int s = src[e];
    const int d = dst[e];
    const float4 v = *reinterpret_cast<const float4*>(H + (long)s * DIM + lane * 4);
    float* o = agg + (long)d * DIM + lane * 4;
    unsafeAtomicAdd(o + 0, v.x);
    unsafeAtomicAdd(o + 1, v.y);
    unsafeAtomicAdd(o + 2, v.z);
    unsafeAtomicAdd(o + 3, v.w);
}

__global__ void layer_mm(const float* __restrict__ agg, float* __restrict__ H,
                         const float* __restrict__ Wgc, const float* __restrict__ bgc,
                         const float* __restrict__ Wres, const float* __restrict__ bres) {
    __shared__ float sA[8][DIM];
    __shared__ float sH[8][DIM];
    const int tid = threadIdx.x;
    const long rowBase = (long)blockIdx.x * 8;
    const int r = tid >> 5;
    const int c = (tid & 31) * 4;
    *reinterpret_cast<float4*>(&sA[r][c]) =
        *reinterpret_cast<const float4*>(agg + (rowBase + r) * DIM + c);
    *reinterpret_cast<float4*>(&sH[r][c]) =
        *reinterpret_cast<const float4*>(H + (rowBase + r) * DIM + c);
    __syncthreads();
    float4 a1 = make_float4(0.f, 0.f, 0.f, 0.f);
    float4 a2 = make_float4(0.f, 0.f, 0.f, 0.f);
    #pragma unroll 8
    for (int k = 0; k < DIM; ++k) {
        const float av = sA[r][k];
        const float hv = sH[r][k];
        const float4 wg = *reinterpret_cast<const float4*>(Wgc + k * DIM + c);
        const float4 wr = *reinterpret_cast<const float4*>(Wres + k * DIM + c);
        a1.x += av * wg.x; a1.y += av * wg.y; a1.z += av * wg.z; a1.w += av * wg.w;
        a2.x += hv * wr.x; a2.y += hv * wr.y; a2.z += hv * wr.z; a2.w += hv * wr.w;
    }
    const float4 bg = *reinterpret_cast<const float4*>(bgc + c);
    const float4 br = *reinterpret_cast<const float4*>(bres + c);
    float4 o;
    o.x = fmaxf(a1.x + bg.x, 0.f) + fmaxf(a2.x + br.x, 0.f);
    o.y = fmaxf(a1.y + bg.y, 0.f) + fmaxf(a2.y + br.y, 0.f);
    o.z = fmaxf(a1.z + bg.z, 0.f) + fmaxf(a2.z + br.z, 0.f);
    o.w = fmaxf(a1.w + bg.w, 0.f) + fmaxf(a2.w + br.w, 0.f);
    *reinterpret_cast<float4*>(H + (rowBase + r) * DIM + c) = o;
}

// ================================================================ launch
extern "C" void kernel_launch(void* const* d_in, const int* in_sizes, int n_in,
                              void* d_out, int out_size, void* d_ws, size_t ws_size,
                              hipStream_t stream) {
    const float* node_feats = (const float*)d_in[0];
    const int*   src        = (const int*)d_in[1];
    const int*   dst        = (const int*)d_in[2];
    const float* W_init     = (const float*)d_in[3];
    const float* W_gc       = (const float*)d_in[4];
    const float* b_gc       = (const float*)d_in[5];
    const float* W_res      = (const float*)d_in[6];
    const float* b_res      = (const float*)d_in[7];

    const size_t HB_BYTES  = (size_t)N_NODES * DIM * sizeof(unsigned short);  // 76,021,760
    const size_t RP_BYTES  = ((size_t)(N_NODES + 1) * 4 + 255) & ~255ull;
    const size_t DEG_BYTES = ((size_t)N_NODES * 4 + 255) & ~255ull;
    const size_t CUR_BYTES = DEG_BYTES;            // cursor; reused as bf16 Wt (196,608 B) after fill_k
    const size_t BS_BYTES  = ((size_t)SCAN_BLOCKS * 4 + 255) & ~255ull;
    const size_t EIDX_BYTES = (size_t)N_EDGES * 4;
    const size_t NEED = 2 * HB_BYTES + RP_BYTES + DEG_BYTES + CUR_BYTES + BS_BYTES + EIDX_BYTES;

    if (ws_size >= NEED) {
        char* w = (char*)d_ws;
        unsigned short* Ha = (unsigned short*)w;      w += HB_BYTES;
        unsigned short* Hb = (unsigned short*)w;      w += HB_BYTES;
        int* rowptr = (int*)w;                        w += RP_BYTES;
        int* deg    = (int*)w;                        w += DEG_BYTES;
        int* cursor = (int*)w;                        w += CUR_BYTES;
        int* bs     = (int*)w;                        w += BS_BYTES;
        int* eidx   = (int*)w;
        unsigned short* Wt = (unsigned short*)cursor; // 6*16384 shorts = 196,608 B <= CUR_BYTES
        float* Hout = (float*)d_out;

        zero_i<<<SCAN_BLOCKS, 256, 0, stream>>>(deg, N_NODES);
        hist_k<<<EDGE_BLOCKS, 256, 0, stream>>>(dst, deg);
        scanA<<<SCAN_BLOCKS, 256, 0, stream>>>(deg, rowptr, bs);
        scanB<<<1, 256, 0, stream>>>(bs, SCAN_BLOCKS);
        scanC<<<SCAN_BLOCKS, 256, 0, stream>>>(deg, rowptr, bs, cursor);
        fill_k<<<EDGE_BLOCKS, 256, 0, stream>>>(src, dst, cursor, eidx);
        wcvt<<<6 * 64, 256, 0, stream>>>(W_gc, W_res, Wt);   // after fill_k: cursor is dead

        init_mm_bf<<<N_NODES / 8, 256, 0, stream>>>(node_feats, W_init, Ha);

        // L0: Ha->Hb ; L1: Hb->Ha ; L2: Ha->d_out (f32)
        layer_mfma<0><<<N_NODES / 32, 256, 0, stream>>>(
            Ha, Hb, nullptr, rowptr, eidx, Wt + 0 * 16384, Wt + 3 * 16384, b_gc, b_res);
        layer_mfma<0><<<N_NODES / 32, 256, 0, stream>>>(
            Hb, Ha, nullptr, rowptr, eidx, Wt + 1 * 16384, Wt + 4 * 16384,
            b_gc + DIM, b_res + DIM);
        layer_mfma<1><<<N_NODES / 32, 256, 0, stream>>>(
            Ha, nullptr, Hout, rowptr, eidx, Wt + 2 * 16384, Wt + 5 * 16384,
            b_gc + 2 * DIM, b_res + 2 * DIM);
    } else {
        // fp32 atomic-scatter fallback
        float* H   = (float*)d_out;
        float* agg = (float*)d_ws;
        const int n4 = N_NODES * DIM / 4;
        init_mm<<<N_NODES / 8, 256, 0, stream>>>(node_feats, W_init, H);
        for (int l = 0; l < N_LAYERS; ++l) {
            zero_f4<<<(n4 + 255) / 256, 256, 0, stream>>>((float4*)agg, n4);
            scatter_add<<<(N_EDGES * 32) / 256, 256, 0, stream>>>(H, src, dst, agg);
            layer_mm<<<N_NODES / 8, 256, 0, stream>>>(agg, H,
                W_gc + (size_t)l * DIM * DIM, b_gc + (size_t)l * DIM,
                W_res + (size_t)l * DIM * DIM, b_res + (size_t)l * DIM);
        }
    }
}

// Round 5
// 917.646 us; speedup vs baseline: 17.2697x; 1.2882x over previous
//
#include <hip/hip_runtime.h>

#define N_NODES 296960
#define N_EDGES 2375680
#define IN_FEATS 75
#define DIM 128
#define N_LAYERS 3
#define SCAN_BLOCKS (N_NODES / 256)      // 1160
#define EDGE_BLOCKS (N_EDGES / 256)      // 9280
#define ECAP 4096                        // staged edge indices (16 KB, aliases both tiles)
#define KPAD 104                         // init LDS row stride (shorts): bank-friendly
#define KUSE 96                          // init K padded to 3x32

static_assert(N_NODES % 256 == 0, "node count divisible by 256");
static_assert(N_EDGES % 256 == 0, "edge count divisible by 256");

typedef __attribute__((ext_vector_type(8))) short s8v;   // 8 bf16 = 4 VGPR MFMA frag
typedef __attribute__((ext_vector_type(4))) float f4v;   // 4 f32 accum frag

__device__ __forceinline__ float u2f(unsigned int x) {
    union { unsigned int u; float f; } v; v.u = x; return v.f;
}
__device__ __forceinline__ unsigned short f2b(float f) {   // f32 -> bf16 RNE
    union { float f; unsigned int u; } v; v.f = f;
    unsigned int r = v.u + 0x7fffu + ((v.u >> 16) & 1u);
    return (unsigned short)(r >> 16);
}
__device__ __forceinline__ void addbf(f4v& a, uint2 q) {   // accumulate 4 bf16 into f32x4
    a.x += u2f(q.x << 16);
    a.y += u2f(q.x & 0xffff0000u);
    a.z += u2f(q.y << 16);
    a.w += u2f(q.y & 0xffff0000u);
}

// ================================================================ CSR build
__global__ void zero_i(int* __restrict__ p, int n) {
    int i = blockIdx.x * blockDim.x + threadIdx.x;
    if (i < n) p[i] = 0;
}

__global__ void hist_k(const int* __restrict__ dst, int* __restrict__ deg) {
    int e = blockIdx.x * 256 + threadIdx.x;
    atomicAdd(&deg[dst[e]], 1);
}

__global__ void scanA(const int* __restrict__ deg, int* __restrict__ inc,
                      int* __restrict__ bs) {
    __shared__ int lds[256];
    const int tid = threadIdx.x;
    const int i = blockIdx.x * 256 + tid;
    const int v = deg[i];
    lds[tid] = v;
    __syncthreads();
    for (int s = 1; s < 256; s <<= 1) {
        int t = (tid >= s) ? lds[tid - s] : 0;
        __syncthreads();
        lds[tid] += t;
        __syncthreads();
    }
    inc[i] = lds[tid];
    if (tid == 255) bs[blockIdx.x] = lds[255];
}

__global__ void scanB(int* __restrict__ bs, int nb) {
    __shared__ int lds[256];
    __shared__ int carry;
    const int tid = threadIdx.x;
    if (tid == 0) carry = 0;
    __syncthreads();
    for (int base = 0; base < nb; base += 256) {
        const int idx = base + tid;
        const int v = (idx < nb) ? bs[idx] : 0;
        lds[tid] = v;
        __syncthreads();
        for (int s = 1; s < 256; s <<= 1) {
            int t = (tid >= s) ? lds[tid - s] : 0;
            __syncthreads();
            lds[tid] += t;
            __syncthreads();
        }
        const int inc = lds[tid];
        const int c = carry;
        __syncthreads();
        if (idx < nb) bs[idx] = c + inc - v;
        if (tid == 255) carry = c + lds[255];
        __syncthreads();
    }
}

__global__ void scanC(const int* __restrict__ deg, int* __restrict__ rowptr,
                      const int* __restrict__ bs, int* __restrict__ cursor) {
    const int i = blockIdx.x * 256 + threadIdx.x;
    const int exc = rowptr[i] - deg[i] + bs[blockIdx.x];
    rowptr[i] = exc;
    cursor[i] = exc;
    if (i == 0) rowptr[N_NODES] = N_EDGES;
}

__global__ void fill_k(const int* __restrict__ src, const int* __restrict__ dst,
                       int* __restrict__ cursor, int* __restrict__ eidx) {
    int e = blockIdx.x * 256 + threadIdx.x;
    int p = atomicAdd(&cursor[dst[e]], 1);
    eidx[p] = src[e];
}

// ================================================================ weight transpose+cvt
// Wt[m][n][k] = bf16(W_m[k][n]) for the 6 layer matrices
__global__ void wcvt(const float* __restrict__ Wgc, const float* __restrict__ Wres,
                     unsigned short* __restrict__ Wt) {
    const int m = blockIdx.x >> 6;
    const int idx = (blockIdx.x & 63) * 256 + threadIdx.x;
    const float* src = (m < 3) ? (Wgc + m * 16384) : (Wres + (m - 3) * 16384);
    const int n = idx >> 7, k = idx & 127;
    Wt[m * 16384 + idx] = f2b(src[k * 128 + n]);
}

// WtI[n][k] = bf16(W_init[k][n]), zero-padded k in [75,96)
__global__ void wcvt_init(const float* __restrict__ Wi, unsigned short* __restrict__ WtI) {
    int idx = blockIdx.x * 256 + threadIdx.x;
    if (idx >= 128 * KUSE) return;
    int n = idx / KUSE, k = idx - n * KUSE;
    WtI[idx] = (k < IN_FEATS) ? f2b(Wi[(size_t)k * DIM + n]) : (unsigned short)0;
}

// ================================================================ h0 = X @ W_init via MFMA -> bf16
__global__ __launch_bounds__(256) void init_mfma(const float* __restrict__ X,
                                                 const unsigned short* __restrict__ WtI,
                                                 unsigned short* __restrict__ H) {
    __shared__ short sX[32][KPAD];   // 6656 B; stride 208 B -> 2-way (free) frag reads
    const int tid = threadIdx.x;
    const int rowBase = blockIdx.x * 32;

    // zero tile (covers the k >= 75 padding)
    int* z = (int*)&sX[0][0];
    #pragma unroll
    for (int i = 0; i < 7; ++i) {
        const int idx = tid + i * 256;
        if (idx < (32 * KPAD) / 2) z[idx] = 0;
    }
    __syncthreads();

    // stage + convert 32 rows of X (coalesced f32 reads)
    for (int idx = tid; idx < 32 * IN_FEATS; idx += 256) {
        const int row = idx / IN_FEATS;
        const int k = idx - row * IN_FEATS;
        sX[row][k] = (short)f2b(X[(size_t)rowBase * IN_FEATS + idx]);
    }
    __syncthreads();

    const int w = tid >> 6;
    const int l = tid & 63;
    const int lr = l & 15;
    const int lk = l >> 4;

    f4v acc[2][2] = {{{0.f,0.f,0.f,0.f},{0.f,0.f,0.f,0.f}},{{0.f,0.f,0.f,0.f},{0.f,0.f,0.f,0.f}}};

    #pragma unroll
    for (int kb = 0; kb < 3; ++kb) {
        const int kofs = kb * 32 + lk * 8;
        s8v a[2], b[2];
        a[0] = *reinterpret_cast<const s8v*>(&sX[lr][kofs]);
        a[1] = *reinterpret_cast<const s8v*>(&sX[16 + lr][kofs]);
        #pragma unroll
        for (int ct = 0; ct < 2; ++ct) {
            const int col = w * 32 + ct * 16 + lr;
            b[ct] = *reinterpret_cast<const s8v*>(WtI + (size_t)col * KUSE + kofs);
        }
        #pragma unroll
        for (int rt = 0; rt < 2; ++rt)
            #pragma unroll
            for (int ct = 0; ct < 2; ++ct)
                acc[rt][ct] = __builtin_amdgcn_mfma_f32_16x16x32_bf16(a[rt], b[ct], acc[rt][ct], 0, 0, 0);
    }

    #pragma unroll
    for (int ct = 0; ct < 2; ++ct) {
        const int col = w * 32 + ct * 16 + lr;
        #pragma unroll
        for (int rt = 0; rt < 2; ++rt)
            #pragma unroll
            for (int r = 0; r < 4; ++r) {
                const int row = rowBase + rt * 16 + lk * 4 + r;
                H[(size_t)row * DIM + col] = f2b(acc[rt][ct][r]);
            }
    }
}

// ================================================================ fused gather + dual MFMA GEMM
template <int LAST>
__global__ __launch_bounds__(256) void layer_mfma(
    const unsigned short* __restrict__ Hin, unsigned short* __restrict__ HoutB,
    float* __restrict__ HoutF,
    const int* __restrict__ rowptr, const int* __restrict__ eidx,
    const unsigned short* __restrict__ WgcT, const unsigned short* __restrict__ WresT,
    const float* __restrict__ bgc, const float* __restrict__ bres) {
    __shared__ short sTiles[2][32][DIM];     // [0]=agg, [1]=own : 16 KB total
    int* sE = (int*)&sTiles[0][0][0];        // aliases both tiles during staging
    char* aggB = (char*)&sTiles[0][0][0];
    char* ownB = (char*)&sTiles[1][0][0];

    const int tid = threadIdx.x;
    const int rowBase = blockIdx.x * 32;

    const int blkBeg = rowptr[rowBase];
    const int blkEnd = rowptr[rowBase + 32];
    const int nE = blkEnd - blkBeg;
    const int nStage = (nE < ECAP) ? nE : ECAP;

    for (int i = tid; i < nStage; i += 256)
        sE[i] = eidx[blkBeg + i];
    __syncthreads();

    // ---- gather: group g handles nodes g*4..g*4+3; 4-deep unrolled loads ----
    const int g = tid >> 5;
    const int lane = tid & 31;
    f4v accs[4];
    uint2 own[4];
    #pragma unroll
    for (int ii = 0; ii < 4; ++ii) {
        const int node = rowBase + g * 4 + ii;
        const int beg = rowptr[node];
        const int end = rowptr[node + 1];
        own[ii] = *reinterpret_cast<const uint2*>(Hin + (size_t)node * DIM + lane * 4);
        f4v a0 = {0.f,0.f,0.f,0.f}, a1 = {0.f,0.f,0.f,0.f};
        f4v a2 = {0.f,0.f,0.f,0.f}, a3 = {0.f,0.f,0.f,0.f};
        int e = beg;
        for (; e + 4 <= end; e += 4) {
            const int o = e - blkBeg;
            const int s0 = (o + 0 < ECAP) ? sE[o + 0] : eidx[e + 0];
            const int s1 = (o + 1 < ECAP) ? sE[o + 1] : eidx[e + 1];
            const int s2 = (o + 2 < ECAP) ? sE[o + 2] : eidx[e + 2];
            const int s3 = (o + 3 < ECAP) ? sE[o + 3] : eidx[e + 3];
            const uint2 q0 = *reinterpret_cast<const uint2*>(Hin + (size_t)s0 * DIM + lane * 4);
            const uint2 q1 = *reinterpret_cast<const uint2*>(Hin + (size_t)s1 * DIM + lane * 4);
            const uint2 q2 = *reinterpret_cast<const uint2*>(Hin + (size_t)s2 * DIM + lane * 4);
            const uint2 q3 = *reinterpret_cast<const uint2*>(Hin + (size_t)s3 * DIM + lane * 4);
            addbf(a0, q0); addbf(a1, q1); addbf(a2, q2); addbf(a3, q3);
        }
        for (; e < end; ++e) {
            const int o = e - blkBeg;
            const int s = (o < ECAP) ? sE[o] : eidx[e];
            addbf(a0, *reinterpret_cast<const uint2*>(Hin + (size_t)s * DIM + lane * 4));
        }
        accs[ii] = (a0 + a1) + (a2 + a3);
    }
    __syncthreads();   // sE dead

    // ---- write swizzled bf16 A-tiles:  byte = row*256 + (kbyte ^ ((row&7)<<4)) ----
    #pragma unroll
    for (int ii = 0; ii < 4; ++ii) {
        const int row = g * 4 + ii;
        const int kbyte = lane * 8;
        const int sw = kbyte ^ ((row & 7) << 4);
        uint2 p;
        p.x = (unsigned)f2b(accs[ii].x) | ((unsigned)f2b(accs[ii].y) << 16);
        p.y = (unsigned)f2b(accs[ii].z) | ((unsigned)f2b(accs[ii].w) << 16);
        *reinterpret_cast<uint2*>(aggB + row * 256 + sw) = p;
        *reinterpret_cast<uint2*>(ownB + row * 256 + sw) = own[ii];
    }
    __syncthreads();

    // ---- dual MFMA GEMM: wave w -> cols [w*32, w*32+32) ----
    const int w = tid >> 6;
    const int l = tid & 63;
    const int lr = l & 15;
    const int lk = l >> 4;

    f4v accG[2][2] = {{{0.f,0.f,0.f,0.f},{0.f,0.f,0.f,0.f}},{{0.f,0.f,0.f,0.f},{0.f,0.f,0.f,0.f}}};
    f4v accR[2][2] = {{{0.f,0.f,0.f,0.f},{0.f,0.f,0.f,0.f}},{{0.f,0.f,0.f,0.f},{0.f,0.f,0.f,0.f}}};

    #pragma unroll
    for (int kb = 0; kb < 4; ++kb) {
        const int kofs = kb * 32 + lk * 8;
        const int kbyte = kofs * 2;
        s8v aG[2], aO[2];
        #pragma unroll
        for (int rt = 0; rt < 2; ++rt) {
            const int row = rt * 16 + lr;
            const int byte = row * 256 + (kbyte ^ ((row & 7) << 4));
            aG[rt] = *reinterpret_cast<const s8v*>(aggB + byte);
            aO[rt] = *reinterpret_cast<const s8v*>(ownB + byte);
        }
        s8v bG[2], bR[2];
        #pragma unroll
        for (int ct = 0; ct < 2; ++ct) {
            const int col = w * 32 + ct * 16 + lr;
            const size_t off = (size_t)col * DIM + kofs;
            bG[ct] = *reinterpret_cast<const s8v*>(WgcT + off);
            bR[ct] = *reinterpret_cast<const s8v*>(WresT + off);
        }
        #pragma unroll
        for (int rt = 0; rt < 2; ++rt) {
            #pragma unroll
            for (int ct = 0; ct < 2; ++ct) {
                accG[rt][ct] = __builtin_amdgcn_mfma_f32_16x16x32_bf16(aG[rt], bG[ct], accG[rt][ct], 0, 0, 0);
                accR[rt][ct] = __builtin_amdgcn_mfma_f32_16x16x32_bf16(aO[rt], bR[ct], accR[rt][ct], 0, 0, 0);
            }
        }
    }

    #pragma unroll
    for (int ct = 0; ct < 2; ++ct) {
        const int col = w * 32 + ct * 16 + lr;
        const float bg = bgc[col];
        const float br = bres[col];
        #pragma unroll
        for (int rt = 0; rt < 2; ++rt) {
            #pragma unroll
            for (int r = 0; r < 4; ++r) {
                const int row = rowBase + rt * 16 + lk * 4 + r;
                const float v = fmaxf(accG[rt][ct][r] + bg, 0.f) + fmaxf(accR[rt][ct][r] + br, 0.f);
                if (LAST) HoutF[(size_t)row * DIM + col] = v;
                else      HoutB[(size_t)row * DIM + col] = f2b(v);
            }
        }
    }
}

// ================================================================ fp32 fallback path
__global__ void init_mm(const float* __restrict__ X, const float* __restrict__ W,
                        float* __restrict__ H) {
    __shared__ float sF[8 * IN_FEATS];
    const int tid = threadIdx.x;
    const long rowBase = (long)blockIdx.x * 8;
    for (int i = tid; i < 8 * IN_FEATS; i += 256)
        sF[i] = X[rowBase * IN_FEATS + i];
    __syncthreads();
    const int r = tid >> 5;
    const int c = (tid & 31) * 4;
    float4 acc = make_float4(0.f, 0.f, 0.f, 0.f);
    for (int k = 0; k < IN_FEATS; ++k) {
        const float a = sF[r * IN_FEATS + k];
        const float4 w = *reinterpret_cast<const float4*>(W + k * DIM + c);
        acc.x += a * w.x; acc.y += a * w.y; acc.z += a * w.z; acc.w += a * w.w;
    }
    *reinterpret_cast<float4*>(H + (rowBase + r) * DIM + c) = acc;
}

__global__ void zero_f4(float4* __restrict__ p, int n4) {
    int i = blockIdx.x * blockDim.x + threadIdx.x;
    if (i < n4) p[i] = make_float4(0.f, 0.f, 0.f, 0.f);
}

__global__ void scatter_add(const float* __restrict__ H, const int* __restrict__ src,
                            const int* __restrict__ dst, float* __restrict__ agg) {
    const long t = (long)blockIdx.x * blockDim.x + threadIdx.x;
    const int e = (int)(t >> 5);
    const int lane = (int)(t & 31);
    if (e >= N_EDGES) return;
    const int s = src[e];
    const int d = dst[e];
    const float4 v = *reinterpret_cast<const float4*>(H + (long)s * DIM + lane * 4);
    float* o = agg + (long)d * DIM + lane * 4;
    unsafeAtomicAdd(o + 0, v.x);
    unsafeAtomicAdd(o + 1, v.y);
    unsafeAtomicAdd(o + 2, v.z);
    unsafeAtomicAdd(o + 3, v.w);
}

__global__ void layer_mm(const float* __restrict__ agg, float* __restrict__ H,
                         const float* __restrict__ Wgc, const float* __restrict__ bgc,
                         const float* __restrict__ Wres, const float* __restrict__ bres) {
    __shared__ float sA[8][DIM];
    __shared__ float sH[8][DIM];
    const int tid = threadIdx.x;
    const long rowBase = (long)blockIdx.x * 8;
    const int r = tid >> 5;
    const int c = (tid & 31) * 4;
    *reinterpret_cast<float4*>(&sA[r][c]) =
        *reinterpret_cast<const float4*>(agg + (rowBase + r) * DIM + c);
    *reinterpret_cast<float4*>(&sH[r][c]) =
        *reinterpret_cast<const float4*>(H + (rowBase + r) * DIM + c);
    __syncthreads();
    float4 a1 = make_float4(0.f, 0.f, 0.f, 0.f);
    float4 a2 = make_float4(0.f, 0.f, 0.f, 0.f);
    #pragma unroll 8
    for (int k = 0; k < DIM; ++k) {
        const float av = sA[r][k];
        const float hv = sH[r][k];
        const float4 wg = *reinterpret_cast<const float4*>(Wgc + k * DIM + c);
        const float4 wr = *reinterpret_cast<const float4*>(Wres + k * DIM + c);
        a1.x += av * wg.x; a1.y += av * wg.y; a1.z += av * wg.z; a1.w += av * wg.w;
        a2.x += hv * wr.x; a2.y += hv * wr.y; a2.z += hv * wr.z; a2.w += hv * wr.w;
    }
    const float4 bg = *reinterpret_cast<const float4*>(bgc + c);
    const float4 br = *reinterpret_cast<const float4*>(bres + c);
    float4 o;
    o.x = fmaxf(a1.x + bg.x, 0.f) + fmaxf(a2.x + br.x, 0.f);
    o.y = fmaxf(a1.y + bg.y, 0.f) + fmaxf(a2.y + br.y, 0.f);
    o.z = fmaxf(a1.z + bg.z, 0.f) + fmaxf(a2.z + br.z, 0.f);
    o.w = fmaxf(a1.w + bg.w, 0.f) + fmaxf(a2.w + br.w, 0.f);
    *reinterpret_cast<float4*>(H + (rowBase + r) * DIM + c) = o;
}

// ================================================================ launch
extern "C" void kernel_launch(void* const* d_in, const int* in_sizes, int n_in,
                              void* d_out, int out_size, void* d_ws, size_t ws_size,
                              hipStream_t stream) {
    const float* node_feats = (const float*)d_in[0];
    const int*   src        = (const int*)d_in[1];
    const int*   dst        = (const int*)d_in[2];
    const float* W_init     = (const float*)d_in[3];
    const float* W_gc       = (const float*)d_in[4];
    const float* b_gc       = (const float*)d_in[5];
    const float* W_res      = (const float*)d_in[6];
    const float* b_res      = (const float*)d_in[7];

    const size_t HB_BYTES  = (size_t)N_NODES * DIM * sizeof(unsigned short);
    const size_t RP_BYTES  = ((size_t)(N_NODES + 1) * 4 + 255) & ~255ull;
    const size_t DEG_BYTES = ((size_t)N_NODES * 4 + 255) & ~255ull;
    const size_t CUR_BYTES = DEG_BYTES;   // cursor; reused as bf16 weights after fill_k
    const size_t BS_BYTES  = ((size_t)SCAN_BLOCKS * 4 + 255) & ~255ull;
    const size_t EIDX_BYTES = (size_t)N_EDGES * 4;
    const size_t NEED = 2 * HB_BYTES + RP_BYTES + DEG_BYTES + CUR_BYTES + BS_BYTES + EIDX_BYTES;

    if (ws_size >= NEED) {
        char* w = (char*)d_ws;
        unsigned short* Ha = (unsigned short*)w;      w += HB_BYTES;
        unsigned short* Hb = (unsigned short*)w;      w += HB_BYTES;
        int* rowptr = (int*)w;                        w += RP_BYTES;
        int* deg    = (int*)w;                        w += DEG_BYTES;
        int* cursor = (int*)w;                        w += CUR_BYTES;
        int* bs     = (int*)w;                        w += BS_BYTES;
        int* eidx   = (int*)w;
        unsigned short* Wt  = (unsigned short*)cursor;        // 6*16384 shorts
        unsigned short* WtI = Wt + 6 * 16384;                 // 128*96 shorts (total 221 KB <= CUR_BYTES)
        float* Hout = (float*)d_out;

        zero_i<<<SCAN_BLOCKS, 256, 0, stream>>>(deg, N_NODES);
        hist_k<<<EDGE_BLOCKS, 256, 0, stream>>>(dst, deg);
        scanA<<<SCAN_BLOCKS, 256, 0, stream>>>(deg, rowptr, bs);
        scanB<<<1, 256, 0, stream>>>(bs, SCAN_BLOCKS);
        scanC<<<SCAN_BLOCKS, 256, 0, stream>>>(deg, rowptr, bs, cursor);
        fill_k<<<EDGE_BLOCKS, 256, 0, stream>>>(src, dst, cursor, eidx);
        wcvt<<<6 * 64, 256, 0, stream>>>(W_gc, W_res, Wt);            // cursor dead now
        wcvt_init<<<(128 * KUSE + 255) / 256, 256, 0, stream>>>(W_init, WtI);

        init_mfma<<<N_NODES / 32, 256, 0, stream>>>(node_feats, WtI, Ha);

        // L0: Ha->Hb ; L1: Hb->Ha ; L2: Ha->d_out (f32)
        layer_mfma<0><<<N_NODES / 32, 256, 0, stream>>>(
            Ha, Hb, nullptr, rowptr, eidx, Wt + 0 * 16384, Wt + 3 * 16384, b_gc, b_res);
        layer_mfma<0><<<N_NODES / 32, 256, 0, stream>>>(
            Hb, Ha, nullptr, rowptr, eidx, Wt + 1 * 16384, Wt + 4 * 16384,
            b_gc + DIM, b_res + DIM);
        layer_mfma<1><<<N_NODES / 32, 256, 0, stream>>>(
            Ha, nullptr, Hout, rowptr, eidx, Wt + 2 * 16384, Wt + 5 * 16384,
            b_gc + 2 * DIM, b_res + 2 * DIM);
    } else {
        // fp32 atomic-scatter fallback
        float* H   = (float*)d_out;
        float* agg = (float*)d_ws;
        const int n4 = N_NODES * DIM / 4;
        init_mm<<<N_NODES / 8, 256, 0, stream>>>(node_feats, W_init, H);
        for (int l = 0; l < N_LAYERS; ++l) {
            zero_f4<<<(n4 + 255) / 256, 256, 0, stream>>>((float4*)agg, n4);
            scatter_add<<<(N_EDGES * 32) / 256, 256, 0, stream>>>(H, src, dst, agg);
            layer_mm<<<N_NODES / 8, 256, 0, stream>>>(agg, H,
                W_gc + (size_t)l * DIM * DIM, b_gc + (size_t)l * DIM,
                W_res + (size_t)l * DIM * DIM, b_res + (size_t)l * DIM);
        }
    }
}

// Round 6
// 788.303 us; speedup vs baseline: 20.1033x; 1.1641x over previous
//
#include <hip/hip_runtime.h>

#define N_NODES 296960
#define N_EDGES 2375680
#define IN_FEATS 75
#define DIM 128
#define N_LAYERS 3
#define SCAN_BLOCKS (N_NODES / 256)      // 1160
#define EDGE_BLOCKS (N_EDGES / 256)      // 9280
#define ECAP 4096                        // staged edge indices (16 KB, aliases both tiles)
#define KPAD 104                         // init LDS row stride (shorts)
#define KUSE 96                          // init K padded to 3x32

static_assert(N_NODES % 256 == 0, "node count divisible by 256");
static_assert(N_EDGES % 256 == 0, "edge count divisible by 256");

typedef __attribute__((ext_vector_type(8))) short s8v;   // 8 bf16 = 4 VGPR MFMA frag
typedef __attribute__((ext_vector_type(4))) float f4v;   // 4 f32 accum frag

__device__ __forceinline__ float u2f(unsigned int x) {
    union { unsigned int u; float f; } v; v.u = x; return v.f;
}
__device__ __forceinline__ unsigned short f2b(float f) {   // f32 -> bf16 RNE
    union { float f; unsigned int u; } v; v.f = f;
    unsigned int r = v.u + 0x7fffu + ((v.u >> 16) & 1u);
    return (unsigned short)(r >> 16);
}
__device__ __forceinline__ void addbf(f4v& a, uint2 q) {   // accumulate 4 bf16 into f32x4
    a.x += u2f(q.x << 16);
    a.y += u2f(q.x & 0xffff0000u);
    a.z += u2f(q.y << 16);
    a.w += u2f(q.y & 0xffff0000u);
}

// ================================================================ CSR build
__global__ void zero_i(int* __restrict__ p, int n) {
    int i = blockIdx.x * blockDim.x + threadIdx.x;
    if (i < n) p[i] = 0;
}

__global__ void hist_k(const int* __restrict__ dst, int* __restrict__ deg) {
    int e = blockIdx.x * 256 + threadIdx.x;
    atomicAdd(&deg[dst[e]], 1);
}

__global__ void scanA(const int* __restrict__ deg, int* __restrict__ inc,
                      int* __restrict__ bs) {
    __shared__ int lds[256];
    const int tid = threadIdx.x;
    const int i = blockIdx.x * 256 + tid;
    const int v = deg[i];
    lds[tid] = v;
    __syncthreads();
    for (int s = 1; s < 256; s <<= 1) {
        int t = (tid >= s) ? lds[tid - s] : 0;
        __syncthreads();
        lds[tid] += t;
        __syncthreads();
    }
    inc[i] = lds[tid];
    if (tid == 255) bs[blockIdx.x] = lds[255];
}

// single-wave exclusive scan of bs[] in place (64 threads, no barriers)
__global__ void scanB(int* __restrict__ bs, int nb) {
    const int lane = threadIdx.x;      // 0..63
    int carry = 0;
    for (int base = 0; base < nb; base += 64) {
        const int idx = base + lane;
        const int v = (idx < nb) ? bs[idx] : 0;
        int x = v;
        #pragma unroll
        for (int s = 1; s < 64; s <<= 1) {
            const int t = __shfl_up(x, s, 64);
            if (lane >= s) x += t;
        }
        if (idx < nb) bs[idx] = carry + x - v;   // exclusive
        carry += __shfl(x, 63, 64);
    }
}

__global__ void scanC(const int* __restrict__ deg, int* __restrict__ rowptr,
                      const int* __restrict__ bs, int* __restrict__ cursor) {
    const int i = blockIdx.x * 256 + threadIdx.x;
    const int exc = rowptr[i] - deg[i] + bs[blockIdx.x];
    rowptr[i] = exc;
    cursor[i] = exc;
    if (i == 0) rowptr[N_NODES] = N_EDGES;
}

__global__ void fill_k(const int* __restrict__ src, const int* __restrict__ dst,
                       int* __restrict__ cursor, int* __restrict__ eidx) {
    int e = blockIdx.x * 256 + threadIdx.x;
    int p = atomicAdd(&cursor[dst[e]], 1);
    eidx[p] = src[e];
}

// ================================================================ weight transpose+cvt
__global__ void wcvt(const float* __restrict__ Wgc, const float* __restrict__ Wres,
                     unsigned short* __restrict__ Wt) {
    const int m = blockIdx.x >> 6;
    const int idx = (blockIdx.x & 63) * 256 + threadIdx.x;
    const float* src = (m < 3) ? (Wgc + m * 16384) : (Wres + (m - 3) * 16384);
    const int n = idx >> 7, k = idx & 127;
    Wt[m * 16384 + idx] = f2b(src[k * 128 + n]);
}

__global__ void wcvt_init(const float* __restrict__ Wi, unsigned short* __restrict__ WtI) {
    int idx = blockIdx.x * 256 + threadIdx.x;
    if (idx >= 128 * KUSE) return;
    int n = idx / KUSE, k = idx - n * KUSE;
    WtI[idx] = (k < IN_FEATS) ? f2b(Wi[(size_t)k * DIM + n]) : (unsigned short)0;
}

// ================================================================ h0 = X @ W_init via MFMA -> bf16
__global__ __launch_bounds__(256) void init_mfma(const float* __restrict__ X,
                                                 const unsigned short* __restrict__ WtI,
                                                 unsigned short* __restrict__ H) {
    __shared__ short sX[32][KPAD];
    const int tid = threadIdx.x;
    const int rowBase = blockIdx.x * 32;

    // stage + convert 32 rows of X (coalesced); zero only pad cols [75,104)
    for (int idx = tid; idx < 32 * IN_FEATS; idx += 256) {
        const int row = idx / IN_FEATS;
        const int k = idx - row * IN_FEATS;
        sX[row][k] = (short)f2b(X[(size_t)rowBase * IN_FEATS + idx]);
    }
    #pragma unroll
    for (int i = 0; i < 4; ++i) {
        const int idx = tid + i * 256;
        const int row = idx >> 5;
        const int col = IN_FEATS + (idx & 31);
        if (col < KPAD) sX[row][col] = 0;
    }
    __syncthreads();

    const int w = tid >> 6;
    const int l = tid & 63;
    const int lr = l & 15;
    const int lk = l >> 4;

    f4v acc[2][2] = {{{0.f,0.f,0.f,0.f},{0.f,0.f,0.f,0.f}},{{0.f,0.f,0.f,0.f},{0.f,0.f,0.f,0.f}}};

    #pragma unroll
    for (int kb = 0; kb < 3; ++kb) {
        const int kofs = kb * 32 + lk * 8;
        s8v a[2], b[2];
        a[0] = *reinterpret_cast<const s8v*>(&sX[lr][kofs]);
        a[1] = *reinterpret_cast<const s8v*>(&sX[16 + lr][kofs]);
        #pragma unroll
        for (int ct = 0; ct < 2; ++ct) {
            const int col = w * 32 + ct * 16 + lr;
            b[ct] = *reinterpret_cast<const s8v*>(WtI + (size_t)col * KUSE + kofs);
        }
        #pragma unroll
        for (int rt = 0; rt < 2; ++rt)
            #pragma unroll
            for (int ct = 0; ct < 2; ++ct)
                acc[rt][ct] = __builtin_amdgcn_mfma_f32_16x16x32_bf16(a[rt], b[ct], acc[rt][ct], 0, 0, 0);
    }

    #pragma unroll
    for (int ct = 0; ct < 2; ++ct) {
        const int col = w * 32 + ct * 16 + lr;
        #pragma unroll
        for (int rt = 0; rt < 2; ++rt)
            #pragma unroll
            for (int r = 0; r < 4; ++r) {
                const int row = rowBase + rt * 16 + lk * 4 + r;
                H[(size_t)row * DIM + col] = f2b(acc[rt][ct][r]);
            }
    }
}

// ================================================================ fused gather + dual MFMA GEMM
template <int LAST>
__global__ __launch_bounds__(256) void layer_mfma(
    const unsigned short* __restrict__ Hin, unsigned short* __restrict__ HoutB,
    float* __restrict__ HoutF,
    const int* __restrict__ rowptr, const int* __restrict__ eidx,
    const unsigned short* __restrict__ WgcT, const unsigned short* __restrict__ WresT,
    const float* __restrict__ bgc, const float* __restrict__ bres) {
    __shared__ short sTiles[2][32][DIM];     // [0]=agg, [1]=own : 16 KB
    int* sE = (int*)&sTiles[0][0][0];        // aliases both tiles during staging
    char* aggB = (char*)&sTiles[0][0][0];
    char* ownB = (char*)&sTiles[1][0][0];

    const int tid = threadIdx.x;
    const int rowBase = blockIdx.x * 32;

    const int blkBeg = rowptr[rowBase];
    const int blkEnd = rowptr[rowBase + 32];
    const int nE = blkEnd - blkBeg;
    const int nStage = (nE < ECAP) ? nE : ECAP;

    for (int i = tid; i < nStage; i += 256)
        sE[i] = eidx[blkBeg + i];
    __syncthreads();

    // ---- gather: group g owns nodes g*4..g*4+3, walked IN PARALLEL (8 loads in flight) ----
    const int g = tid >> 5;
    const int lane = tid & 31;
    const unsigned short* HinL = Hin + lane * 4;

    int begv[4], endv[4], rel[4];
    f4v acc[4];
    uint2 own[4];
    int md = 0;
    #pragma unroll
    for (int ii = 0; ii < 4; ++ii) {
        const int node = rowBase + g * 4 + ii;
        begv[ii] = rowptr[node];
        endv[ii] = rowptr[node + 1];
        rel[ii] = begv[ii] - blkBeg;
        own[ii] = *reinterpret_cast<const uint2*>(HinL + (size_t)node * DIM);
        acc[ii] = (f4v){0.f, 0.f, 0.f, 0.f};
        const int d = endv[ii] - begv[ii];
        md = (d > md) ? d : md;
    }

    if (nE <= ECAP) {
        // hot path: all indices in LDS, no cap checks
        for (int t = 0; t < md; t += 2) {
            #pragma unroll
            for (int ii = 0; ii < 4; ++ii) {
                const int ea = begv[ii] + t;
                const int eb = ea + 1;
                uint2 qa = make_uint2(0u, 0u), qb = make_uint2(0u, 0u);
                if (ea < endv[ii])
                    qa = *reinterpret_cast<const uint2*>(HinL + (size_t)sE[rel[ii] + t] * DIM);
                if (eb < endv[ii])
                    qb = *reinterpret_cast<const uint2*>(HinL + (size_t)sE[rel[ii] + t + 1] * DIM);
                addbf(acc[ii], qa);
                addbf(acc[ii], qb);
            }
        }
    } else {
        // rare fallback: read indices straight from global
        #pragma unroll
        for (int ii = 0; ii < 4; ++ii) {
            for (int e = begv[ii]; e < endv[ii]; ++e) {
                const int s = eidx[e];
                addbf(acc[ii], *reinterpret_cast<const uint2*>(HinL + (size_t)s * DIM));
            }
        }
    }
    __syncthreads();   // sE dead

    // ---- write swizzled bf16 A-tiles:  byte = row*256 + (kbyte ^ ((row&7)<<4)) ----
    #pragma unroll
    for (int ii = 0; ii < 4; ++ii) {
        const int row = g * 4 + ii;
        const int kbyte = lane * 8;
        const int sw = kbyte ^ ((row & 7) << 4);
        uint2 p;
        p.x = (unsigned)f2b(acc[ii].x) | ((unsigned)f2b(acc[ii].y) << 16);
        p.y = (unsigned)f2b(acc[ii].z) | ((unsigned)f2b(acc[ii].w) << 16);
        *reinterpret_cast<uint2*>(aggB + row * 256 + sw) = p;
        *reinterpret_cast<uint2*>(ownB + row * 256 + sw) = own[ii];
    }
    __syncthreads();

    // ---- dual MFMA GEMM: wave w -> cols [w*32, w*32+32) ----
    const int w = tid >> 6;
    const int l = tid & 63;
    const int lr = l & 15;
    const int lk = l >> 4;

    f4v accG[2][2] = {{{0.f,0.f,0.f,0.f},{0.f,0.f,0.f,0.f}},{{0.f,0.f,0.f,0.f},{0.f,0.f,0.f,0.f}}};
    f4v accR[2][2] = {{{0.f,0.f,0.f,0.f},{0.f,0.f,0.f,0.f}},{{0.f,0.f,0.f,0.f},{0.f,0.f,0.f,0.f}}};

    #pragma unroll
    for (int kb = 0; kb < 4; ++kb) {
        const int kofs = kb * 32 + lk * 8;
        const int kbyte = kofs * 2;
        s8v aG[2], aO[2];
        #pragma unroll
        for (int rt = 0; rt < 2; ++rt) {
            const int row = rt * 16 + lr;
            const int byte = row * 256 + (kbyte ^ ((row & 7) << 4));
            aG[rt] = *reinterpret_cast<const s8v*>(aggB + byte);
            aO[rt] = *reinterpret_cast<const s8v*>(ownB + byte);
        }
        s8v bG[2], bR[2];
        #pragma unroll
        for (int ct = 0; ct < 2; ++ct) {
            const int col = w * 32 + ct * 16 + lr;
            const size_t off = (size_t)col * DIM + kofs;
            bG[ct] = *reinterpret_cast<const s8v*>(WgcT + off);
            bR[ct] = *reinterpret_cast<const s8v*>(WresT + off);
        }
        #pragma unroll
        for (int rt = 0; rt < 2; ++rt) {
            #pragma unroll
            for (int ct = 0; ct < 2; ++ct) {
                accG[rt][ct] = __builtin_amdgcn_mfma_f32_16x16x32_bf16(aG[rt], bG[ct], accG[rt][ct], 0, 0, 0);
                accR[rt][ct] = __builtin_amdgcn_mfma_f32_16x16x32_bf16(aO[rt], bR[ct], accR[rt][ct], 0, 0, 0);
            }
        }
    }

    #pragma unroll
    for (int ct = 0; ct < 2; ++ct) {
        const int col = w * 32 + ct * 16 + lr;
        const float bg = bgc[col];
        const float br = bres[col];
        #pragma unroll
        for (int rt = 0; rt < 2; ++rt) {
            #pragma unroll
            for (int r = 0; r < 4; ++r) {
                const int row = rowBase + rt * 16 + lk * 4 + r;
                const float v = fmaxf(accG[rt][ct][r] + bg, 0.f) + fmaxf(accR[rt][ct][r] + br, 0.f);
                if (LAST) HoutF[(size_t)row * DIM + col] = v;
                else      HoutB[(size_t)row * DIM + col] = f2b(v);
            }
        }
    }
}

// ================================================================ fp32 fallback path
__global__ void init_mm(const float* __restrict__ X, const float* __restrict__ W,
                        float* __restrict__ H) {
    __shared__ float sF[8 * IN_FEATS];
    const int tid = threadIdx.x;
    const long rowBase = (long)blockIdx.x * 8;
    for (int i = tid; i < 8 * IN_FEATS; i += 256)
        sF[i] = X[rowBase * IN_FEATS + i];
    __syncthreads();
    const int r = tid >> 5;
    const int c = (tid & 31) * 4;
    float4 acc = make_float4(0.f, 0.f, 0.f, 0.f);
    for (int k = 0; k < IN_FEATS; ++k) {
        const float a = sF[r * IN_FEATS + k];
        const float4 w = *reinterpret_cast<const float4*>(W + k * DIM + c);
        acc.x += a * w.x; acc.y += a * w.y; acc.z += a * w.z; acc.w += a * w.w;
    }
    *reinterpret_cast<float4*>(H + (rowBase + r) * DIM + c) = acc;
}

__global__ void zero_f4(float4* __restrict__ p, int n4) {
    int i = blockIdx.x * blockDim.x + threadIdx.x;
    if (i < n4) p[i] = make_float4(0.f, 0.f, 0.f, 0.f);
}

__global__ void scatter_add(const float* __restrict__ H, const int* __restrict__ src,
                            const int* __restrict__ dst, float* __restrict__ agg) {
    const long t = (long)blockIdx.x * blockDim.x + threadIdx.x;
    const int e = (int)(t >> 5);
    const int lane = (int)(t & 31);
    if (e >= N_EDGES) return;
    const int s = src[e];
    const int d = dst[e];
    const float4 v = *reinterpret_cast<const float4*>(H + (long)s * DIM + lane * 4);
    float* o = agg + (long)d * DIM + lane * 4;
    unsafeAtomicAdd(o + 0, v.x);
    unsafeAtomicAdd(o + 1, v.y);
    unsafeAtomicAdd(o + 2, v.z);
    unsafeAtomicAdd(o + 3, v.w);
}

__global__ void layer_mm(const float* __restrict__ agg, float* __restrict__ H,
                         const float* __restrict__ Wgc, const float* __restrict__ bgc,
                         const float* __restrict__ Wres, const float* __restrict__ bres) {
    __shared__ float sA[8][DIM];
    __shared__ float sH[8][DIM];
    const int tid = threadIdx.x;
    const long rowBase = (long)blockIdx.x * 8;
    const int r = tid >> 5;
    const int c = (tid & 31) * 4;
    *reinterpret_cast<float4*>(&sA[r][c]) =
        *reinterpret_cast<const float4*>(agg + (rowBase + r) * DIM + c);
    *reinterpret_cast<float4*>(&sH[r][c]) =
        *reinterpret_cast<const float4*>(H + (rowBase + r) * DIM + c);
    __syncthreads();
    float4 a1 = make_float4(0.f, 0.f, 0.f, 0.f);
    float4 a2 = make_float4(0.f, 0.f, 0.f, 0.f);
    #pragma unroll 8
    for (int k = 0; k < DIM; ++k) {
        const float av = sA[r][k];
        const float hv = sH[r][k];
        const float4 wg = *reinterpret_cast<const float4*>(Wgc + k * DIM + c);
        const float4 wr = *reinterpret_cast<const float4*>(Wres + k * DIM + c);
        a1.x += av * wg.x; a1.y += av * wg.y; a1.z += av * wg.z; a1.w += av * wg.w;
        a2.x += hv * wr.x; a2.y += hv * wr.y; a2.z += hv * wr.z; a2.w += hv * wr.w;
    }
    const float4 bg = *reinterpret_cast<const float4*>(bgc + c);
    const float4 br = *reinterpret_cast<const float4*>(bres + c);
    float4 o;
    o.x = fmaxf(a1.x + bg.x, 0.f) + fmaxf(a2.x + br.x, 0.f);
    o.y = fmaxf(a1.y + bg.y, 0.f) + fmaxf(a2.y + br.y, 0.f);
    o.z = fmaxf(a1.z + bg.z, 0.f) + fmaxf(a2.z + br.z, 0.f);
    o.w = fmaxf(a1.w + bg.w, 0.f) + fmaxf(a2.w + br.w, 0.f);
    *reinterpret_cast<float4*>(H + (rowBase + r) * DIM + c) = o;
}

// ================================================================ launch
extern "C" void kernel_launch(void* const* d_in, const int* in_sizes, int n_in,
                              void* d_out, int out_size, void* d_ws, size_t ws_size,
                              hipStream_t stream) {
    const float* node_feats = (const float*)d_in[0];
    const int*   src        = (const int*)d_in[1];
    const int*   dst        = (const int*)d_in[2];
    const float* W_init     = (const float*)d_in[3];
    const float* W_gc       = (const float*)d_in[4];
    const float* b_gc       = (const float*)d_in[5];
    const float* W_res      = (const float*)d_in[6];
    const float* b_res      = (const float*)d_in[7];

    const size_t HB_BYTES  = (size_t)N_NODES * DIM * sizeof(unsigned short);
    const size_t RP_BYTES  = ((size_t)(N_NODES + 1) * 4 + 255) & ~255ull;
    const size_t DEG_BYTES = ((size_t)N_NODES * 4 + 255) & ~255ull;
    const size_t CUR_BYTES = DEG_BYTES;   // cursor; reused as bf16 weights after fill_k
    const size_t BS_BYTES  = ((size_t)SCAN_BLOCKS * 4 + 255) & ~255ull;
    const size_t EIDX_BYTES = (size_t)N_EDGES * 4;
    const size_t NEED = 2 * HB_BYTES + RP_BYTES + DEG_BYTES + CUR_BYTES + BS_BYTES + EIDX_BYTES;

    if (ws_size >= NEED) {
        char* w = (char*)d_ws;
        unsigned short* Ha = (unsigned short*)w;      w += HB_BYTES;
        unsigned short* Hb = (unsigned short*)w;      w += HB_BYTES;
        int* rowptr = (int*)w;                        w += RP_BYTES;
        int* deg    = (int*)w;                        w += DEG_BYTES;
        int* cursor = (int*)w;                        w += CUR_BYTES;
        int* bs     = (int*)w;                        w += BS_BYTES;
        int* eidx   = (int*)w;
        unsigned short* Wt  = (unsigned short*)cursor;
        unsigned short* WtI = Wt + 6 * 16384;
        float* Hout = (float*)d_out;

        zero_i<<<SCAN_BLOCKS, 256, 0, stream>>>(deg, N_NODES);
        hist_k<<<EDGE_BLOCKS, 256, 0, stream>>>(dst, deg);
        scanA<<<SCAN_BLOCKS, 256, 0, stream>>>(deg, rowptr, bs);
        scanB<<<1, 64, 0, stream>>>(bs, SCAN_BLOCKS);
        scanC<<<SCAN_BLOCKS, 256, 0, stream>>>(deg, rowptr, bs, cursor);
        fill_k<<<EDGE_BLOCKS, 256, 0, stream>>>(src, dst, cursor, eidx);
        wcvt<<<6 * 64, 256, 0, stream>>>(W_gc, W_res, Wt);
        wcvt_init<<<(128 * KUSE + 255) / 256, 256, 0, stream>>>(W_init, WtI);

        init_mfma<<<N_NODES / 32, 256, 0, stream>>>(node_feats, WtI, Ha);

        layer_mfma<0><<<N_NODES / 32, 256, 0, stream>>>(
            Ha, Hb, nullptr, rowptr, eidx, Wt + 0 * 16384, Wt + 3 * 16384, b_gc, b_res);
        layer_mfma<0><<<N_NODES / 32, 256, 0, stream>>>(
            Hb, Ha, nullptr, rowptr, eidx, Wt + 1 * 16384, Wt + 4 * 16384,
            b_gc + DIM, b_res + DIM);
        layer_mfma<1><<<N_NODES / 32, 256, 0, stream>>>(
            Ha, nullptr, Hout, rowptr, eidx, Wt + 2 * 16384, Wt + 5 * 16384,
            b_gc + 2 * DIM, b_res + 2 * DIM);
    } else {
        float* H   = (float*)d_out;
        float* agg = (float*)d_ws;
        const int n4 = N_NODES * DIM / 4;
        init_mm<<<N_NODES / 8, 256, 0, stream>>>(node_feats, W_init, H);
        for (int l = 0; l < N_LAYERS; ++l) {
            zero_f4<<<(n4 + 255) / 256, 256, 0, stream>>>((float4*)agg, n4);
            scatter_add<<<(N_EDGES * 32) / 256, 256, 0, stream>>>(H, src, dst, agg);
            layer_mm<<<N_NODES / 8, 256, 0, stream>>>(agg, H,
                W_gc + (size_t)l * DIM * DIM, b_gc + (size_t)l * DIM,
                W_res + (size_t)l * DIM * DIM, b_res + (size_t)l * DIM);
        }
    }
}

// Round 7
// 615.377 us; speedup vs baseline: 25.7524x; 1.2810x over previous
//
#include <hip/hip_runtime.h>

#define N_NODES 296960
#define N_EDGES 2375680
#define IN_FEATS 75
#define DIM 128
#define N_LAYERS 3
#define ECAP 4096                        // staged edge indices (16 KB, aliases both tiles)
#define KPAD 104                         // init LDS row stride (shorts)
#define KUSE 96                          // init K padded to 3x32
#define NCHUNK 128                       // CSR super-chunks
#define CHN (N_NODES / NCHUNK)           // 2320 nodes per chunk (dstLow: 12 bits; src: 19 bits)
#define ETILE 2048                       // edges per bucketing block
#define EBLKS (N_EDGES / ETILE)          // 1160
#define CVPT 5                           // scan values/thread: 512*5 = 2560 >= 2320

static_assert(N_NODES % 256 == 0, "node count divisible by 256");
static_assert(N_EDGES % ETILE == 0, "edge count divisible by tile");
static_assert(NCHUNK * CHN == N_NODES, "chunks cover nodes exactly");

typedef __attribute__((ext_vector_type(8))) short s8v;   // 8 bf16 = 4 VGPR MFMA frag
typedef __attribute__((ext_vector_type(4))) float f4v;   // 4 f32 accum frag

__device__ __forceinline__ float u2f(unsigned int x) {
    union { unsigned int u; float f; } v; v.u = x; return v.f;
}
__device__ __forceinline__ unsigned short f2b(float f) {   // f32 -> bf16 RNE
    union { float f; unsigned int u; } v; v.f = f;
    unsigned int r = v.u + 0x7fffu + ((v.u >> 16) & 1u);
    return (unsigned short)(r >> 16);
}
__device__ __forceinline__ void addbf(f4v& a, uint2 q) {   // accumulate 4 bf16 into f32x4
    a.x += u2f(q.x << 16);
    a.y += u2f(q.x & 0xffff0000u);
    a.z += u2f(q.y << 16);
    a.w += u2f(q.y & 0xffff0000u);
}

// ================================================================ CSR build (locality-aware 2-pass sort)
__global__ void zero_i(int* __restrict__ p, int n) {
    int i = blockIdx.x * blockDim.x + threadIdx.x;
    if (i < n) p[i] = 0;
}

// 128-bin coarse histogram of dst/CHN (LDS-staged, 128 global atomics/block)
__global__ __launch_bounds__(256) void coarse_hist(const int* __restrict__ dst,
                                                   int* __restrict__ ccnt) {
    __shared__ int cnt[NCHUNK];
    const int tid = threadIdx.x;
    if (tid < NCHUNK) cnt[tid] = 0;
    __syncthreads();
    const int base = blockIdx.x * ETILE;
    #pragma unroll
    for (int i = 0; i < ETILE / 256; ++i) {
        const int d = dst[base + i * 256 + tid];
        atomicAdd(&cnt[d / CHN], 1);
    }
    __syncthreads();
    if (tid < NCHUNK && cnt[tid] > 0) atomicAdd(&ccnt[tid], cnt[tid]);
}

// exclusive scan of 128 chunk counts -> bucketBase[0..128]
__global__ void coarse_scan(const int* __restrict__ ccnt, int* __restrict__ bucketBase) {
    __shared__ int lds[NCHUNK];
    const int tid = threadIdx.x;
    if (tid < NCHUNK) lds[tid] = ccnt[tid];
    __syncthreads();
    if (tid == 0) {
        int run = 0;
        for (int k = 0; k < NCHUNK; ++k) {
            const int v = lds[k];
            lds[k] = run;
            run += v;
        }
        bucketBase[NCHUNK] = run;   // == N_EDGES
    }
    __syncthreads();
    if (tid < NCHUNK) bucketBase[tid] = lds[tid];
}

// scatter packed edges into chunk buckets; per-block exclusive runs -> L2-coalesced writes
__global__ __launch_bounds__(256) void bucket_pass(
    const int* __restrict__ src, const int* __restrict__ dst,
    const int* __restrict__ bucketBase, int* __restrict__ bcur,
    unsigned int* __restrict__ bedge) {
    __shared__ int cnt[NCHUNK];
    __shared__ int cnt2[NCHUNK];
    __shared__ int basei[NCHUNK];
    const int tid = threadIdx.x;
    if (tid < NCHUNK) { cnt[tid] = 0; cnt2[tid] = 0; }
    __syncthreads();

    const int base = blockIdx.x * ETILE;
    int s8[ETILE / 256], b8[ETILE / 256], dl8[ETILE / 256];
    #pragma unroll
    for (int i = 0; i < ETILE / 256; ++i) {
        const int e = base + i * 256 + tid;
        s8[i] = src[e];
        const int d = dst[e];
        b8[i] = d / CHN;
        dl8[i] = d - b8[i] * CHN;
        atomicAdd(&cnt[b8[i]], 1);
    }
    __syncthreads();
    if (tid < NCHUNK && cnt[tid] > 0)
        basei[tid] = bucketBase[tid] + atomicAdd(&bcur[tid], cnt[tid]);
    __syncthreads();
    #pragma unroll
    for (int i = 0; i < ETILE / 256; ++i) {
        const int pos = basei[b8[i]] + atomicAdd(&cnt2[b8[i]], 1);
        bedge[pos] = ((unsigned int)dl8[i] << 19) | (unsigned int)s8[i];
    }
}

// per-chunk: histogram -> scan -> rowptr (coalesced) -> eidx scatter (L2-local segment)
__global__ __launch_bounds__(512) void csr_pass(
    const unsigned int* __restrict__ bedge, const int* __restrict__ bucketBase,
    int* __restrict__ rowptr, int* __restrict__ eidx) {
    __shared__ int cnt[512 * CVPT];   // 2560 (>= CHN), 10 KB
    __shared__ int wexcl[9];
    const int tid = threadIdx.x;
    const int c = blockIdx.x;
    const int nodeBase = c * CHN;
    const int segBeg = bucketBase[c];
    const int nseg = bucketBase[c + 1] - segBeg;

    #pragma unroll
    for (int j = 0; j < CVPT; ++j) cnt[tid * CVPT + j] = 0;
    __syncthreads();

    for (int i = tid; i < nseg; i += 512)
        atomicAdd(&cnt[bedge[segBeg + i] >> 19], 1);
    __syncthreads();

    // block exclusive scan over 2560 entries -> absolute segment offsets
    int v[CVPT];
    int s = 0;
    #pragma unroll
    for (int j = 0; j < CVPT; ++j) { v[j] = cnt[tid * CVPT + j]; s += v[j]; }
    const int lane = tid & 63, wid = tid >> 6;
    int x = s;
    #pragma unroll
    for (int st = 1; st < 64; st <<= 1) {
        const int t = __shfl_up(x, st, 64);
        if (lane >= st) x += t;
    }
    if (lane == 63) wexcl[wid + 1] = x;
    __syncthreads();
    if (tid == 0) {
        wexcl[0] = 0;
        for (int k = 1; k <= 8; ++k) wexcl[k] += wexcl[k - 1];
    }
    __syncthreads();
    int run = segBeg + wexcl[wid] + (x - s);
    #pragma unroll
    for (int j = 0; j < CVPT; ++j) { cnt[tid * CVPT + j] = run; run += v[j]; }
    __syncthreads();

    // rowptr segment (coalesced)
    for (int n = tid; n < CHN; n += 512)
        rowptr[nodeBase + n] = cnt[n];
    if (c == NCHUNK - 1 && tid == 0) rowptr[N_NODES] = N_EDGES;
    __syncthreads();

    // eidx scatter: all writes land in this chunk's contiguous segment (L2-local)
    for (int i = tid; i < nseg; i += 512) {
        const unsigned int p = bedge[segBeg + i];
        const int pos = atomicAdd(&cnt[p >> 19], 1);
        eidx[pos] = (int)(p & 0x7FFFFu);
    }
}

// ================================================================ weight transpose+cvt
__global__ void wcvt(const float* __restrict__ Wgc, const float* __restrict__ Wres,
                     unsigned short* __restrict__ Wt) {
    const int m = blockIdx.x >> 6;
    const int idx = (blockIdx.x & 63) * 256 + threadIdx.x;
    const float* src = (m < 3) ? (Wgc + m * 16384) : (Wres + (m - 3) * 16384);
    const int n = idx >> 7, k = idx & 127;
    Wt[m * 16384 + idx] = f2b(src[k * 128 + n]);
}

__global__ void wcvt_init(const float* __restrict__ Wi, unsigned short* __restrict__ WtI) {
    int idx = blockIdx.x * 256 + threadIdx.x;
    if (idx >= 128 * KUSE) return;
    int n = idx / KUSE, k = idx - n * KUSE;
    WtI[idx] = (k < IN_FEATS) ? f2b(Wi[(size_t)k * DIM + n]) : (unsigned short)0;
}

// ================================================================ h0 = X @ W_init via MFMA -> bf16
__global__ __launch_bounds__(256) void init_mfma(const float* __restrict__ X,
                                                 const unsigned short* __restrict__ WtI,
                                                 unsigned short* __restrict__ H) {
    __shared__ short sX[32][KPAD];
    const int tid = threadIdx.x;
    const int rowBase = blockIdx.x * 32;

    for (int idx = tid; idx < 32 * IN_FEATS; idx += 256) {
        const int row = idx / IN_FEATS;
        const int k = idx - row * IN_FEATS;
        sX[row][k] = (short)f2b(X[(size_t)rowBase * IN_FEATS + idx]);
    }
    #pragma unroll
    for (int i = 0; i < 4; ++i) {
        const int idx = tid + i * 256;
        const int row = idx >> 5;
        const int col = IN_FEATS + (idx & 31);
        if (col < KPAD) sX[row][col] = 0;
    }
    __syncthreads();

    const int w = tid >> 6;
    const int l = tid & 63;
    const int lr = l & 15;
    const int lk = l >> 4;

    f4v acc[2][2] = {{{0.f,0.f,0.f,0.f},{0.f,0.f,0.f,0.f}},{{0.f,0.f,0.f,0.f},{0.f,0.f,0.f,0.f}}};

    #pragma unroll
    for (int kb = 0; kb < 3; ++kb) {
        const int kofs = kb * 32 + lk * 8;
        s8v a[2], b[2];
        a[0] = *reinterpret_cast<const s8v*>(&sX[lr][kofs]);
        a[1] = *reinterpret_cast<const s8v*>(&sX[16 + lr][kofs]);
        #pragma unroll
        for (int ct = 0; ct < 2; ++ct) {
            const int col = w * 32 + ct * 16 + lr;
            b[ct] = *reinterpret_cast<const s8v*>(WtI + (size_t)col * KUSE + kofs);
        }
        #pragma unroll
        for (int rt = 0; rt < 2; ++rt)
            #pragma unroll
            for (int ct = 0; ct < 2; ++ct)
                acc[rt][ct] = __builtin_amdgcn_mfma_f32_16x16x32_bf16(a[rt], b[ct], acc[rt][ct], 0, 0, 0);
    }

    #pragma unroll
    for (int ct = 0; ct < 2; ++ct) {
        const int col = w * 32 + ct * 16 + lr;
        #pragma unroll
        for (int rt = 0; rt < 2; ++rt)
            #pragma unroll
            for (int r = 0; r < 4; ++r) {
                const int row = rowBase + rt * 16 + lk * 4 + r;
                H[(size_t)row * DIM + col] = f2b(acc[rt][ct][r]);
            }
    }
}

// ================================================================ fused gather + dual MFMA GEMM
template <int LAST>
__global__ __launch_bounds__(256) void layer_mfma(
    const unsigned short* __restrict__ Hin, unsigned short* __restrict__ HoutB,
    float* __restrict__ HoutF,
    const int* __restrict__ rowptr, const int* __restrict__ eidx,
    const unsigned short* __restrict__ WgcT, const unsigned short* __restrict__ WresT,
    const float* __restrict__ bgc, const float* __restrict__ bres) {
    __shared__ short sTiles[2][32][DIM];     // [0]=agg, [1]=own : 16 KB
    int* sE = (int*)&sTiles[0][0][0];        // aliases both tiles during staging
    char* aggB = (char*)&sTiles[0][0][0];
    char* ownB = (char*)&sTiles[1][0][0];

    const int tid = threadIdx.x;
    const int rowBase = blockIdx.x * 32;

    const int blkBeg = rowptr[rowBase];
    const int blkEnd = rowptr[rowBase + 32];
    const int nE = blkEnd - blkBeg;
    const int nStage = (nE < ECAP) ? nE : ECAP;

    for (int i = tid; i < nStage; i += 256)
        sE[i] = eidx[blkBeg + i];
    __syncthreads();

    // ---- gather: group g owns nodes g*4..g*4+3, walked IN PARALLEL ----
    const int g = tid >> 5;
    const int lane = tid & 31;
    const unsigned short* HinL = Hin + lane * 4;

    int begv[4], endv[4], rel[4];
    f4v acc[4];
    uint2 own[4];
    int md = 0;
    #pragma unroll
    for (int ii = 0; ii < 4; ++ii) {
        const int node = rowBase + g * 4 + ii;
        begv[ii] = rowptr[node];
        endv[ii] = rowptr[node + 1];
        rel[ii] = begv[ii] - blkBeg;
        own[ii] = *reinterpret_cast<const uint2*>(HinL + (size_t)node * DIM);
        acc[ii] = (f4v){0.f, 0.f, 0.f, 0.f};
        const int d = endv[ii] - begv[ii];
        md = (d > md) ? d : md;
    }

    if (nE <= ECAP) {
        for (int t = 0; t < md; t += 2) {
            #pragma unroll
            for (int ii = 0; ii < 4; ++ii) {
                const int ea = begv[ii] + t;
                const int eb = ea + 1;
                uint2 qa = make_uint2(0u, 0u), qb = make_uint2(0u, 0u);
                if (ea < endv[ii])
                    qa = *reinterpret_cast<const uint2*>(HinL + (size_t)sE[rel[ii] + t] * DIM);
                if (eb < endv[ii])
                    qb = *reinterpret_cast<const uint2*>(HinL + (size_t)sE[rel[ii] + t + 1] * DIM);
                addbf(acc[ii], qa);
                addbf(acc[ii], qb);
            }
        }
    } else {
        #pragma unroll
        for (int ii = 0; ii < 4; ++ii) {
            for (int e = begv[ii]; e < endv[ii]; ++e) {
                const int s = eidx[e];
                addbf(acc[ii], *reinterpret_cast<const uint2*>(HinL + (size_t)s * DIM));
            }
        }
    }
    __syncthreads();   // sE dead

    // ---- write swizzled bf16 A-tiles:  byte = row*256 + (kbyte ^ ((row&7)<<4)) ----
    #pragma unroll
    for (int ii = 0; ii < 4; ++ii) {
        const int row = g * 4 + ii;
        const int kbyte = lane * 8;
        const int sw = kbyte ^ ((row & 7) << 4);
        uint2 p;
        p.x = (unsigned)f2b(acc[ii].x) | ((unsigned)f2b(acc[ii].y) << 16);
        p.y = (unsigned)f2b(acc[ii].z) | ((unsigned)f2b(acc[ii].w) << 16);
        *reinterpret_cast<uint2*>(aggB + row * 256 + sw) = p;
        *reinterpret_cast<uint2*>(ownB + row * 256 + sw) = own[ii];
    }
    __syncthreads();

    // ---- dual MFMA GEMM: wave w -> cols [w*32, w*32+32) ----
    const int w = tid >> 6;
    const int l = tid & 63;
    const int lr = l & 15;
    const int lk = l >> 4;

    f4v accG[2][2] = {{{0.f,0.f,0.f,0.f},{0.f,0.f,0.f,0.f}},{{0.f,0.f,0.f,0.f},{0.f,0.f,0.f,0.f}}};
    f4v accR[2][2] = {{{0.f,0.f,0.f,0.f},{0.f,0.f,0.f,0.f}},{{0.f,0.f,0.f,0.f},{0.f,0.f,0.f,0.f}}};

    #pragma unroll
    for (int kb = 0; kb < 4; ++kb) {
        const int kofs = kb * 32 + lk * 8;
        const int kbyte = kofs * 2;
        s8v aG[2], aO[2];
        #pragma unroll
        for (int rt = 0; rt < 2; ++rt) {
            const int row = rt * 16 + lr;
            const int byte = row * 256 + (kbyte ^ ((row & 7) << 4));
            aG[rt] = *reinterpret_cast<const s8v*>(aggB + byte);
            aO[rt] = *reinterpret_cast<const s8v*>(ownB + byte);
        }
        s8v bG[2], bR[2];
        #pragma unroll
        for (int ct = 0; ct < 2; ++ct) {
            const int col = w * 32 + ct * 16 + lr;
            const size_t off = (size_t)col * DIM + kofs;
            bG[ct] = *reinterpret_cast<const s8v*>(WgcT + off);
            bR[ct] = *reinterpret_cast<const s8v*>(WresT + off);
        }
        #pragma unroll
        for (int rt = 0; rt < 2; ++rt) {
            #pragma unroll
            for (int ct = 0; ct < 2; ++ct) {
                accG[rt][ct] = __builtin_amdgcn_mfma_f32_16x16x32_bf16(aG[rt], bG[ct], accG[rt][ct], 0, 0, 0);
                accR[rt][ct] = __builtin_amdgcn_mfma_f32_16x16x32_bf16(aO[rt], bR[ct], accR[rt][ct], 0, 0, 0);
            }
        }
    }

    #pragma unroll
    for (int ct = 0; ct < 2; ++ct) {
        const int col = w * 32 + ct * 16 + lr;
        const float bg = bgc[col];
        const float br = bres[col];
        #pragma unroll
        for (int rt = 0; rt < 2; ++rt) {
            #pragma unroll
            for (int r = 0; r < 4; ++r) {
                const int row = rowBase + rt * 16 + lk * 4 + r;
                const float v = fmaxf(accG[rt][ct][r] + bg, 0.f) + fmaxf(accR[rt][ct][r] + br, 0.f);
                if (LAST) HoutF[(size_t)row * DIM + col] = v;
                else      HoutB[(size_t)row * DIM + col] = f2b(v);
            }
        }
    }
}

// ================================================================ fp32 fallback path
__global__ void init_mm(const float* __restrict__ X, const float* __restrict__ W,
                        float* __restrict__ H) {
    __shared__ float sF[8 * IN_FEATS];
    const int tid = threadIdx.x;
    const long rowBase = (long)blockIdx.x * 8;
    for (int i = tid; i < 8 * IN_FEATS; i += 256)
        sF[i] = X[rowBase * IN_FEATS + i];
    __syncthreads();
    const int r = tid >> 5;
    const int c = (tid & 31) * 4;
    float4 acc = make_float4(0.f, 0.f, 0.f, 0.f);
    for (int k = 0; k < IN_FEATS; ++k) {
        const float a = sF[r * IN_FEATS + k];
        const float4 w = *reinterpret_cast<const float4*>(W + k * DIM + c);
        acc.x += a * w.x; acc.y += a * w.y; acc.z += a * w.z; acc.w += a * w.w;
    }
    *reinterpret_cast<float4*>(H + (rowBase + r) * DIM + c) = acc;
}

__global__ void zero_f4(float4* __restrict__ p, int n4) {
    int i = blockIdx.x * blockDim.x + threadIdx.x;
    if (i < n4) p[i] = make_float4(0.f, 0.f, 0.f, 0.f);
}

__global__ void scatter_add(const float* __restrict__ H, const int* __restrict__ src,
                            const int* __restrict__ dst, float* __restrict__ agg) {
    const long t = (long)blockIdx.x * blockDim.x + threadIdx.x;
    const int e = (int)(t >> 5);
    const int lane = (int)(t & 31);
    if (e >= N_EDGES) return;
    const int s = src[e];
    const int d = dst[e];
    const float4 v = *reinterpret_cast<const float4*>(H + (long)s * DIM + lane * 4);
    float* o = agg + (long)d * DIM + lane * 4;
    unsafeAtomicAdd(o + 0, v.x);
    unsafeAtomicAdd(o + 1, v.y);
    unsafeAtomicAdd(o + 2, v.z);
    unsafeAtomicAdd(o + 3, v.w);
}

__global__ void layer_mm(const float* __restrict__ agg, float* __restrict__ H,
                         const float* __restrict__ Wgc, const float* __restrict__ bgc,
                         const float* __restrict__ Wres, const float* __restrict__ bres) {
    __shared__ float sA[8][DIM];
    __shared__ float sH[8][DIM];
    const int tid = threadIdx.x;
    const long rowBase = (long)blockIdx.x * 8;
    const int r = tid >> 5;
    const int c = (tid & 31) * 4;
    *reinterpret_cast<float4*>(&sA[r][c]) =
        *reinterpret_cast<const float4*>(agg + (rowBase + r) * DIM + c);
    *reinterpret_cast<float4*>(&sH[r][c]) =
        *reinterpret_cast<const float4*>(H + (rowBase + r) * DIM + c);
    __syncthreads();
    float4 a1 = make_float4(0.f, 0.f, 0.f, 0.f);
    float4 a2 = make_float4(0.f, 0.f, 0.f, 0.f);
    #pragma unroll 8
    for (int k = 0; k < DIM; ++k) {
        const float av = sA[r][k];
        const float hv = sH[r][k];
        const float4 wg = *reinterpret_cast<const float4*>(Wgc + k * DIM + c);
        const float4 wr = *reinterpret_cast<const float4*>(Wres + k * DIM + c);
        a1.x += av * wg.x; a1.y += av * wg.y; a1.z += av * wg.z; a1.w += av * wg.w;
        a2.x += hv * wr.x; a2.y += hv * wr.y; a2.z += hv * wr.z; a2.w += hv * wr.w;
    }
    const float4 bg = *reinterpret_cast<const float4*>(bgc + c);
    const float4 br = *reinterpret_cast<const float4*>(bres + c);
    float4 o;
    o.x = fmaxf(a1.x + bg.x, 0.f) + fmaxf(a2.x + br.x, 0.f);
    o.y = fmaxf(a1.y + bg.y, 0.f) + fmaxf(a2.y + br.y, 0.f);
    o.z = fmaxf(a1.z + bg.z, 0.f) + fmaxf(a2.z + br.z, 0.f);
    o.w = fmaxf(a1.w + bg.w, 0.f) + fmaxf(a2.w + br.w, 0.f);
    *reinterpret_cast<float4*>(H + (rowBase + r) * DIM + c) = o;
}

// ================================================================ launch
extern "C" void kernel_launch(void* const* d_in, const int* in_sizes, int n_in,
                              void* d_out, int out_size, void* d_ws, size_t ws_size,
                              hipStream_t stream) {
    const float* node_feats = (const float*)d_in[0];
    const int*   src        = (const int*)d_in[1];
    const int*   dst        = (const int*)d_in[2];
    const float* W_init     = (const float*)d_in[3];
    const float* W_gc       = (const float*)d_in[4];
    const float* b_gc       = (const float*)d_in[5];
    const float* W_res      = (const float*)d_in[6];
    const float* b_res      = (const float*)d_in[7];

    // ws layout kept identical to prior rounds (NEED unchanged)
    const size_t HB_BYTES  = (size_t)N_NODES * DIM * sizeof(unsigned short);
    const size_t RP_BYTES  = ((size_t)(N_NODES + 1) * 4 + 255) & ~255ull;
    const size_t DEG_BYTES = ((size_t)N_NODES * 4 + 255) & ~255ull;
    const size_t CUR_BYTES = DEG_BYTES;
    const size_t BS_BYTES  = (((size_t)(N_NODES / 256)) * 4 + 255) & ~255ull;
    const size_t EIDX_BYTES = (size_t)N_EDGES * 4;
    const size_t NEED = 2 * HB_BYTES + RP_BYTES + DEG_BYTES + CUR_BYTES + BS_BYTES + EIDX_BYTES;

    if (ws_size >= NEED) {
        char* w = (char*)d_ws;
        unsigned short* Ha = (unsigned short*)w;      w += HB_BYTES;
        unsigned short* Hb = (unsigned short*)w;      w += HB_BYTES;
        int* rowptr = (int*)w;                        w += RP_BYTES;
        int* small  = (int*)w;                        w += DEG_BYTES;   // ccnt/bcur/bucketBase
        int* wtarea = (int*)w;                        w += CUR_BYTES;   // bf16 weights
        w += BS_BYTES;                                                   // (unused)
        int* eidx   = (int*)w;

        int* ccnt       = small;                 // [128]
        int* bcur       = small + NCHUNK;        // [128]
        int* bucketBase = small + 2 * NCHUNK;    // [129]
        unsigned int* bedge = (unsigned int*)Hb; // aliases Hb (dead until layer 0 output)
        unsigned short* Wt  = (unsigned short*)wtarea;   // 6*16384 shorts
        unsigned short* WtI = Wt + 6 * 16384;            // 128*96 shorts
        float* Hout = (float*)d_out;

        // ---- CSR build: coarse hist -> scan -> bucket -> per-chunk sort ----
        zero_i<<<1, 256, 0, stream>>>(small, 2 * NCHUNK);
        coarse_hist<<<EBLKS, 256, 0, stream>>>(dst, ccnt);
        coarse_scan<<<1, NCHUNK, 0, stream>>>(ccnt, bucketBase);
        bucket_pass<<<EBLKS, 256, 0, stream>>>(src, dst, bucketBase, bcur, bedge);
        csr_pass<<<NCHUNK, 512, 0, stream>>>(bedge, bucketBase, rowptr, eidx);

        // ---- weights + init ----
        wcvt<<<6 * 64, 256, 0, stream>>>(W_gc, W_res, Wt);
        wcvt_init<<<(128 * KUSE + 255) / 256, 256, 0, stream>>>(W_init, WtI);
        init_mfma<<<N_NODES / 32, 256, 0, stream>>>(node_feats, WtI, Ha);

        // L0: Ha->Hb ; L1: Hb->Ha ; L2: Ha->d_out (f32)
        layer_mfma<0><<<N_NODES / 32, 256, 0, stream>>>(
            Ha, Hb, nullptr, rowptr, eidx, Wt + 0 * 16384, Wt + 3 * 16384, b_gc, b_res);
        layer_mfma<0><<<N_NODES / 32, 256, 0, stream>>>(
            Hb, Ha, nullptr, rowptr, eidx, Wt + 1 * 16384, Wt + 4 * 16384,
            b_gc + DIM, b_res + DIM);
        layer_mfma<1><<<N_NODES / 32, 256, 0, stream>>>(
            Ha, nullptr, Hout, rowptr, eidx, Wt + 2 * 16384, Wt + 5 * 16384,
            b_gc + 2 * DIM, b_res + 2 * DIM);
    } else {
        float* H   = (float*)d_out;
        float* agg = (float*)d_ws;
        const int n4 = N_NODES * DIM / 4;
        init_mm<<<N_NODES / 8, 256, 0, stream>>>(node_feats, W_init, H);
        for (int l = 0; l < N_LAYERS; ++l) {
            zero_f4<<<(n4 + 255) / 256, 256, 0, stream>>>((float4*)agg, n4);
            scatter_add<<<(N_EDGES * 32) / 256, 256, 0, stream>>>(H, src, dst, agg);
            layer_mm<<<N_NODES / 8, 256, 0, stream>>>(agg, H,
                W_gc + (size_t)l * DIM * DIM, b_gc + (size_t)l * DIM,
                W_res + (size_t)l * DIM * DIM, b_res + (size_t)l * DIM);
        }
    }
}

// Round 8
// 608.620 us; speedup vs baseline: 26.0384x; 1.0111x over previous
//
#include <hip/hip_runtime.h>

#define N_NODES 296960
#define N_EDGES 2375680
#define IN_FEATS 75
#define DIM 128
#define N_LAYERS 3
#define ECAP 4096                        // staged edge indices (16 KB, aliases both tiles)
#define KPAD 104                         // init LDS row stride (shorts)
#define KUSE 96                          // init K padded to 3x32
#define NCHUNK 128                       // CSR super-chunks
#define CHN (N_NODES / NCHUNK)           // 2320 nodes per chunk (dstLow: 12 bits; src: 19 bits)
#define ETILE 2048                       // edges per bucketing block
#define EBLKS (N_EDGES / ETILE)          // 1160
#define CVPT 5                           // scan values/thread: 512*5 = 2560 >= 2320

static_assert(N_NODES % 256 == 0, "node count divisible by 256");
static_assert(N_EDGES % ETILE == 0, "edge count divisible by tile");
static_assert(NCHUNK * CHN == N_NODES, "chunks cover nodes exactly");

typedef __attribute__((ext_vector_type(8))) short s8v;   // 8 bf16 = 4 VGPR MFMA frag
typedef __attribute__((ext_vector_type(4))) float f4v;   // 4 f32 accum frag

__device__ __forceinline__ float u2f(unsigned int x) {
    union { unsigned int u; float f; } v; v.u = x; return v.f;
}
__device__ __forceinline__ unsigned short f2b(float f) {   // f32 -> bf16 RNE
    union { float f; unsigned int u; } v; v.f = f;
    unsigned int r = v.u + 0x7fffu + ((v.u >> 16) & 1u);
    return (unsigned short)(r >> 16);
}
__device__ __forceinline__ void addbf8(f4v& a, f4v& b, uint4 q) {  // 8 bf16 -> f32 accum
    a.x += u2f(q.x << 16); a.y += u2f(q.x & 0xffff0000u);
    a.z += u2f(q.y << 16); a.w += u2f(q.y & 0xffff0000u);
    b.x += u2f(q.z << 16); b.y += u2f(q.z & 0xffff0000u);
    b.z += u2f(q.w << 16); b.w += u2f(q.w & 0xffff0000u);
}

// ================================================================ CSR build (locality-aware 2-pass sort)
__global__ void zero_i(int* __restrict__ p, int n) {
    int i = blockIdx.x * blockDim.x + threadIdx.x;
    if (i < n) p[i] = 0;
}

__global__ __launch_bounds__(256) void coarse_hist(const int* __restrict__ dst,
                                                   int* __restrict__ ccnt) {
    __shared__ int cnt[NCHUNK];
    const int tid = threadIdx.x;
    if (tid < NCHUNK) cnt[tid] = 0;
    __syncthreads();
    const int base = blockIdx.x * ETILE;
    #pragma unroll
    for (int i = 0; i < ETILE / 256; ++i) {
        const int d = dst[base + i * 256 + tid];
        atomicAdd(&cnt[d / CHN], 1);
    }
    __syncthreads();
    if (tid < NCHUNK && cnt[tid] > 0) atomicAdd(&ccnt[tid], cnt[tid]);
}

__global__ void coarse_scan(const int* __restrict__ ccnt, int* __restrict__ bucketBase) {
    __shared__ int lds[NCHUNK];
    const int tid = threadIdx.x;
    if (tid < NCHUNK) lds[tid] = ccnt[tid];
    __syncthreads();
    if (tid == 0) {
        int run = 0;
        for (int k = 0; k < NCHUNK; ++k) {
            const int v = lds[k];
            lds[k] = run;
            run += v;
        }
        bucketBase[NCHUNK] = run;
    }
    __syncthreads();
    if (tid < NCHUNK) bucketBase[tid] = lds[tid];
}

__global__ __launch_bounds__(256) void bucket_pass(
    const int* __restrict__ src, const int* __restrict__ dst,
    const int* __restrict__ bucketBase, int* __restrict__ bcur,
    unsigned int* __restrict__ bedge) {
    __shared__ int cnt[NCHUNK];
    __shared__ int cnt2[NCHUNK];
    __shared__ int basei[NCHUNK];
    const int tid = threadIdx.x;
    if (tid < NCHUNK) { cnt[tid] = 0; cnt2[tid] = 0; }
    __syncthreads();

    const int base = blockIdx.x * ETILE;
    int s8[ETILE / 256], b8[ETILE / 256], dl8[ETILE / 256];
    #pragma unroll
    for (int i = 0; i < ETILE / 256; ++i) {
        const int e = base + i * 256 + tid;
        s8[i] = src[e];
        const int d = dst[e];
        b8[i] = d / CHN;
        dl8[i] = d - b8[i] * CHN;
        atomicAdd(&cnt[b8[i]], 1);
    }
    __syncthreads();
    if (tid < NCHUNK && cnt[tid] > 0)
        basei[tid] = bucketBase[tid] + atomicAdd(&bcur[tid], cnt[tid]);
    __syncthreads();
    #pragma unroll
    for (int i = 0; i < ETILE / 256; ++i) {
        const int pos = basei[b8[i]] + atomicAdd(&cnt2[b8[i]], 1);
        bedge[pos] = ((unsigned int)dl8[i] << 19) | (unsigned int)s8[i];
    }
}

__global__ __launch_bounds__(512) void csr_pass(
    const unsigned int* __restrict__ bedge, const int* __restrict__ bucketBase,
    int* __restrict__ rowptr, int* __restrict__ eidx) {
    __shared__ int cnt[512 * CVPT];
    __shared__ int wexcl[9];
    const int tid = threadIdx.x;
    const int c = blockIdx.x;
    const int nodeBase = c * CHN;
    const int segBeg = bucketBase[c];
    const int nseg = bucketBase[c + 1] - segBeg;

    #pragma unroll
    for (int j = 0; j < CVPT; ++j) cnt[tid * CVPT + j] = 0;
    __syncthreads();

    for (int i = tid; i < nseg; i += 512)
        atomicAdd(&cnt[bedge[segBeg + i] >> 19], 1);
    __syncthreads();

    int v[CVPT];
    int s = 0;
    #pragma unroll
    for (int j = 0; j < CVPT; ++j) { v[j] = cnt[tid * CVPT + j]; s += v[j]; }
    const int lane = tid & 63, wid = tid >> 6;
    int x = s;
    #pragma unroll
    for (int st = 1; st < 64; st <<= 1) {
        const int t = __shfl_up(x, st, 64);
        if (lane >= st) x += t;
    }
    if (lane == 63) wexcl[wid + 1] = x;
    __syncthreads();
    if (tid == 0) {
        wexcl[0] = 0;
        for (int k = 1; k <= 8; ++k) wexcl[k] += wexcl[k - 1];
    }
    __syncthreads();
    int run = segBeg + wexcl[wid] + (x - s);
    #pragma unroll
    for (int j = 0; j < CVPT; ++j) { cnt[tid * CVPT + j] = run; run += v[j]; }
    __syncthreads();

    for (int n = tid; n < CHN; n += 512)
        rowptr[nodeBase + n] = cnt[n];
    if (c == NCHUNK - 1 && tid == 0) rowptr[N_NODES] = N_EDGES;
    __syncthreads();

    for (int i = tid; i < nseg; i += 512) {
        const unsigned int p = bedge[segBeg + i];
        const int pos = atomicAdd(&cnt[p >> 19], 1);
        eidx[pos] = (int)(p & 0x7FFFFu);
    }
}

// ================================================================ weight transpose+cvt
__global__ void wcvt(const float* __restrict__ Wgc, const float* __restrict__ Wres,
                     unsigned short* __restrict__ Wt) {
    const int m = blockIdx.x >> 6;
    const int idx = (blockIdx.x & 63) * 256 + threadIdx.x;
    const float* src = (m < 3) ? (Wgc + m * 16384) : (Wres + (m - 3) * 16384);
    const int n = idx >> 7, k = idx & 127;
    Wt[m * 16384 + idx] = f2b(src[k * 128 + n]);
}

__global__ void wcvt_init(const float* __restrict__ Wi, unsigned short* __restrict__ WtI) {
    int idx = blockIdx.x * 256 + threadIdx.x;
    if (idx >= 128 * KUSE) return;
    int n = idx / KUSE, k = idx - n * KUSE;
    WtI[idx] = (k < IN_FEATS) ? f2b(Wi[(size_t)k * DIM + n]) : (unsigned short)0;
}

// ================================================================ h0 = X @ W_init via MFMA -> bf16
__global__ __launch_bounds__(256) void init_mfma(const float* __restrict__ X,
                                                 const unsigned short* __restrict__ WtI,
                                                 unsigned short* __restrict__ H) {
    __shared__ short sX[32][KPAD];
    const int tid = threadIdx.x;
    const int rowBase = blockIdx.x * 32;

    for (int idx = tid; idx < 32 * IN_FEATS; idx += 256) {
        const int row = idx / IN_FEATS;
        const int k = idx - row * IN_FEATS;
        sX[row][k] = (short)f2b(X[(size_t)rowBase * IN_FEATS + idx]);
    }
    #pragma unroll
    for (int i = 0; i < 4; ++i) {
        const int idx = tid + i * 256;
        const int row = idx >> 5;
        const int col = IN_FEATS + (idx & 31);
        if (col < KPAD) sX[row][col] = 0;
    }
    __syncthreads();

    const int w = tid >> 6;
    const int l = tid & 63;
    const int lr = l & 15;
    const int lk = l >> 4;

    f4v acc[2][2] = {{{0.f,0.f,0.f,0.f},{0.f,0.f,0.f,0.f}},{{0.f,0.f,0.f,0.f},{0.f,0.f,0.f,0.f}}};

    #pragma unroll
    for (int kb = 0; kb < 3; ++kb) {
        const int kofs = kb * 32 + lk * 8;
        s8v a[2], b[2];
        a[0] = *reinterpret_cast<const s8v*>(&sX[lr][kofs]);
        a[1] = *reinterpret_cast<const s8v*>(&sX[16 + lr][kofs]);
        #pragma unroll
        for (int ct = 0; ct < 2; ++ct) {
            const int col = w * 32 + ct * 16 + lr;
            b[ct] = *reinterpret_cast<const s8v*>(WtI + (size_t)col * KUSE + kofs);
        }
        #pragma unroll
        for (int rt = 0; rt < 2; ++rt)
            #pragma unroll
            for (int ct = 0; ct < 2; ++ct)
                acc[rt][ct] = __builtin_amdgcn_mfma_f32_16x16x32_bf16(a[rt], b[ct], acc[rt][ct], 0, 0, 0);
    }

    #pragma unroll
    for (int ct = 0; ct < 2; ++ct) {
        const int col = w * 32 + ct * 16 + lr;
        #pragma unroll
        for (int rt = 0; rt < 2; ++rt)
            #pragma unroll
            for (int r = 0; r < 4; ++r) {
                const int row = rowBase + rt * 16 + lk * 4 + r;
                H[(size_t)row * DIM + col] = f2b(acc[rt][ct][r]);
            }
    }
}

// ================================================================ fused gather + dual MFMA GEMM
// gather: 16 groups of 16 lanes, 2 nodes/group, uint4 row-loads, 4-deep (32 rows/wave in flight)
// epilogue (bf16): LDS transpose -> coalesced 16B/lane full-line writes
template <int LAST>
__global__ __launch_bounds__(256) void layer_mfma(
    const unsigned short* __restrict__ Hin, unsigned short* __restrict__ HoutB,
    float* __restrict__ HoutF,
    const int* __restrict__ rowptr, const int* __restrict__ eidx,
    const unsigned short* __restrict__ WgcT, const unsigned short* __restrict__ WresT,
    const float* __restrict__ bgc, const float* __restrict__ bres) {
    __shared__ short sTiles[2][32][DIM];     // [0]=agg, [1]=own : 16 KB
    int* sE = (int*)&sTiles[0][0][0];        // aliases both tiles during staging
    char* aggB = (char*)&sTiles[0][0][0];
    char* ownB = (char*)&sTiles[1][0][0];

    const int tid = threadIdx.x;
    const int rowBase = blockIdx.x * 32;

    const int blkBeg = rowptr[rowBase];
    const int blkEnd = rowptr[rowBase + 32];
    const int nE = blkEnd - blkBeg;
    const int nStage = (nE < ECAP) ? nE : ECAP;

    for (int i = tid; i < nStage; i += 256)
        sE[i] = eidx[blkBeg + i];
    __syncthreads();

    // ---- gather ----
    const int gg = tid >> 4;          // 16 groups
    const int lane16 = tid & 15;
    const unsigned short* HinL = Hin + lane16 * 8;   // 16 B per lane

    int begv[2], endv[2], rel[2];
    f4v accA[2], accB[2];
    uint4 own[2];
    int md = 0;
    #pragma unroll
    for (int ii = 0; ii < 2; ++ii) {
        const int node = rowBase + gg * 2 + ii;
        begv[ii] = rowptr[node];
        endv[ii] = rowptr[node + 1];
        rel[ii] = begv[ii] - blkBeg;
        own[ii] = *reinterpret_cast<const uint4*>(HinL + (size_t)node * DIM);
        accA[ii] = (f4v){0.f, 0.f, 0.f, 0.f};
        accB[ii] = (f4v){0.f, 0.f, 0.f, 0.f};
        const int d = endv[ii] - begv[ii];
        md = (d > md) ? d : md;
    }

    if (nE <= ECAP) {
        for (int t = 0; t < md; t += 4) {
            uint4 q[2][4];
            #pragma unroll
            for (int ii = 0; ii < 2; ++ii)
                #pragma unroll
                for (int j = 0; j < 4; ++j) {
                    q[ii][j] = make_uint4(0u, 0u, 0u, 0u);
                    const int e = begv[ii] + t + j;
                    if (e < endv[ii])
                        q[ii][j] = *reinterpret_cast<const uint4*>(
                            HinL + (size_t)sE[rel[ii] + t + j] * DIM);
                }
            #pragma unroll
            for (int ii = 0; ii < 2; ++ii)
                #pragma unroll
                for (int j = 0; j < 4; ++j)
                    addbf8(accA[ii], accB[ii], q[ii][j]);
        }
    } else {
        #pragma unroll
        for (int ii = 0; ii < 2; ++ii)
            for (int e = begv[ii]; e < endv[ii]; ++e)
                addbf8(accA[ii], accB[ii],
                       *reinterpret_cast<const uint4*>(HinL + (size_t)eidx[e] * DIM));
    }
    __syncthreads();   // sE dead

    // ---- write swizzled bf16 A-tiles: byte = row*256 + (kbyte ^ ((row&7)<<4)), 16B units ----
    #pragma unroll
    for (int ii = 0; ii < 2; ++ii) {
        const int row = gg * 2 + ii;
        const int kbyte = lane16 * 16;
        const int sw = kbyte ^ ((row & 7) << 4);
        uint4 p;
        p.x = (unsigned)f2b(accA[ii].x) | ((unsigned)f2b(accA[ii].y) << 16);
        p.y = (unsigned)f2b(accA[ii].z) | ((unsigned)f2b(accA[ii].w) << 16);
        p.z = (unsigned)f2b(accB[ii].x) | ((unsigned)f2b(accB[ii].y) << 16);
        p.w = (unsigned)f2b(accB[ii].z) | ((unsigned)f2b(accB[ii].w) << 16);
        *reinterpret_cast<uint4*>(aggB + row * 256 + sw) = p;
        *reinterpret_cast<uint4*>(ownB + row * 256 + sw) = own[ii];
    }
    __syncthreads();

    // ---- dual MFMA GEMM: wave w -> cols [w*32, w*32+32) ----
    const int w = tid >> 6;
    const int l = tid & 63;
    const int lr = l & 15;
    const int lk = l >> 4;

    f4v accG[2][2] = {{{0.f,0.f,0.f,0.f},{0.f,0.f,0.f,0.f}},{{0.f,0.f,0.f,0.f},{0.f,0.f,0.f,0.f}}};
    f4v accR[2][2] = {{{0.f,0.f,0.f,0.f},{0.f,0.f,0.f,0.f}},{{0.f,0.f,0.f,0.f},{0.f,0.f,0.f,0.f}}};

    #pragma unroll
    for (int kb = 0; kb < 4; ++kb) {
        const int kofs = kb * 32 + lk * 8;
        const int kbyte = kofs * 2;
        s8v aG[2], aO[2];
        #pragma unroll
        for (int rt = 0; rt < 2; ++rt) {
            const int row = rt * 16 + lr;
            const int byte = row * 256 + (kbyte ^ ((row & 7) << 4));
            aG[rt] = *reinterpret_cast<const s8v*>(aggB + byte);
            aO[rt] = *reinterpret_cast<const s8v*>(ownB + byte);
        }
        s8v bG[2], bR[2];
        #pragma unroll
        for (int ct = 0; ct < 2; ++ct) {
            const int col = w * 32 + ct * 16 + lr;
            const size_t off = (size_t)col * DIM + kofs;
            bG[ct] = *reinterpret_cast<const s8v*>(WgcT + off);
            bR[ct] = *reinterpret_cast<const s8v*>(WresT + off);
        }
        #pragma unroll
        for (int rt = 0; rt < 2; ++rt) {
            #pragma unroll
            for (int ct = 0; ct < 2; ++ct) {
                accG[rt][ct] = __builtin_amdgcn_mfma_f32_16x16x32_bf16(aG[rt], bG[ct], accG[rt][ct], 0, 0, 0);
                accR[rt][ct] = __builtin_amdgcn_mfma_f32_16x16x32_bf16(aO[rt], bR[ct], accR[rt][ct], 0, 0, 0);
            }
        }
    }

    if (LAST) {
        // f32 direct: 16 lanes x 4B = full 64B line per quarter-wave store
        #pragma unroll
        for (int ct = 0; ct < 2; ++ct) {
            const int col = w * 32 + ct * 16 + lr;
            const float bg = bgc[col];
            const float br = bres[col];
            #pragma unroll
            for (int rt = 0; rt < 2; ++rt)
                #pragma unroll
                for (int r = 0; r < 4; ++r) {
                    const int row = rowBase + rt * 16 + lk * 4 + r;
                    HoutF[(size_t)row * DIM + col] =
                        fmaxf(accG[rt][ct][r] + bg, 0.f) + fmaxf(accR[rt][ct][r] + br, 0.f);
                }
        }
    } else {
        // bf16: LDS transpose -> coalesced full-line writes
        __syncthreads();                       // all waves done reading A-tiles
        short* eOut = (short*)aggB;            // 32*128 shorts = 8 KB
        #pragma unroll
        for (int ct = 0; ct < 2; ++ct) {
            const int col = w * 32 + ct * 16 + lr;
            const float bg = bgc[col];
            const float br = bres[col];
            #pragma unroll
            for (int rt = 0; rt < 2; ++rt)
                #pragma unroll
                for (int r = 0; r < 4; ++r) {
                    const int row = rt * 16 + lk * 4 + r;
                    eOut[row * DIM + col] = (short)f2b(
                        fmaxf(accG[rt][ct][r] + bg, 0.f) + fmaxf(accR[rt][ct][r] + br, 0.f));
                }
        }
        __syncthreads();
        #pragma unroll
        for (int i = 0; i < 2; ++i) {
            const int id = tid + i * 256;      // 0..511 uint4s
            const int row = id >> 4;
            const int col8 = (id & 15) * 8;    // shorts
            *reinterpret_cast<uint4*>(HoutB + (size_t)(rowBase + row) * DIM + col8) =
                *reinterpret_cast<const uint4*>(eOut + row * DIM + col8);
        }
    }
}

// ================================================================ fp32 fallback path
__global__ void init_mm(const float* __restrict__ X, const float* __restrict__ W,
                        float* __restrict__ H) {
    __shared__ float sF[8 * IN_FEATS];
    const int tid = threadIdx.x;
    const long rowBase = (long)blockIdx.x * 8;
    for (int i = tid; i < 8 * IN_FEATS; i += 256)
        sF[i] = X[rowBase * IN_FEATS + i];
    __syncthreads();
    const int r = tid >> 5;
    const int c = (tid & 31) * 4;
    float4 acc = make_float4(0.f, 0.f, 0.f, 0.f);
    for (int k = 0; k < IN_FEATS; ++k) {
        const float a = sF[r * IN_FEATS + k];
        const float4 w = *reinterpret_cast<const float4*>(W + k * DIM + c);
        acc.x += a * w.x; acc.y += a * w.y; acc.z += a * w.z; acc.w += a * w.w;
    }
    *reinterpret_cast<float4*>(H + (rowBase + r) * DIM + c) = acc;
}

__global__ void zero_f4(float4* __restrict__ p, int n4) {
    int i = blockIdx.x * blockDim.x + threadIdx.x;
    if (i < n4) p[i] = make_float4(0.f, 0.f, 0.f, 0.f);
}

__global__ void scatter_add(const float* __restrict__ H, const int* __restrict__ src,
                            const int* __restrict__ dst, float* __restrict__ agg) {
    const long t = (long)blockIdx.x * blockDim.x + threadIdx.x;
    const int e = (int)(t >> 5);
    const int lane = (int)(t & 31);
    if (e >= N_EDGES) return;
    const int s = src[e];
    const int d = dst[e];
    const float4 v = *reinterpret_cast<const float4*>(H + (long)s * DIM + lane * 4);
    float* o = agg + (long)d * DIM + lane * 4;
    unsafeAtomicAdd(o + 0, v.x);
    unsafeAtomicAdd(o + 1, v.y);
    unsafeAtomicAdd(o + 2, v.z);
    unsafeAtomicAdd(o + 3, v.w);
}

__global__ void layer_mm(const float* __restrict__ agg, float* __restrict__ H,
                         const float* __restrict__ Wgc, const float* __restrict__ bgc,
                         const float* __restrict__ Wres, const float* __restrict__ bres) {
    __shared__ float sA[8][DIM];
    __shared__ float sH[8][DIM];
    const int tid = threadIdx.x;
    const long rowBase = (long)blockIdx.x * 8;
    const int r = tid >> 5;
    const int c = (tid & 31) * 4;
    *reinterpret_cast<float4*>(&sA[r][c]) =
        *reinterpret_cast<const float4*>(agg + (rowBase + r) * DIM + c);
    *reinterpret_cast<float4*>(&sH[r][c]) =
        *reinterpret_cast<const float4*>(H + (rowBase + r) * DIM + c);
    __syncthreads();
    float4 a1 = make_float4(0.f, 0.f, 0.f, 0.f);
    float4 a2 = make_float4(0.f, 0.f, 0.f, 0.f);
    #pragma unroll 8
    for (int k = 0; k < DIM; ++k) {
        const float av = sA[r][k];
        const float hv = sH[r][k];
        const float4 wg = *reinterpret_cast<const float4*>(Wgc + k * DIM + c);
        const float4 wr = *reinterpret_cast<const float4*>(Wres + k * DIM + c);
        a1.x += av * wg.x; a1.y += av * wg.y; a1.z += av * wg.z; a1.w += av * wg.w;
        a2.x += hv * wr.x; a2.y += hv * wr.y; a2.z += hv * wr.z; a2.w += hv * wr.w;
    }
    const float4 bg = *reinterpret_cast<const float4*>(bgc + c);
    const float4 br = *reinterpret_cast<const float4*>(bres + c);
    float4 o;
    o.x = fmaxf(a1.x + bg.x, 0.f) + fmaxf(a2.x + br.x, 0.f);
    o.y = fmaxf(a1.y + bg.y, 0.f) + fmaxf(a2.y + br.y, 0.f);
    o.z = fmaxf(a1.z + bg.z, 0.f) + fmaxf(a2.z + br.z, 0.f);
    o.w = fmaxf(a1.w + bg.w, 0.f) + fmaxf(a2.w + br.w, 0.f);
    *reinterpret_cast<float4*>(H + (rowBase + r) * DIM + c) = o;
}

// ================================================================ launch
extern "C" void kernel_launch(void* const* d_in, const int* in_sizes, int n_in,
                              void* d_out, int out_size, void* d_ws, size_t ws_size,
                              hipStream_t stream) {
    const float* node_feats = (const float*)d_in[0];
    const int*   src        = (const int*)d_in[1];
    const int*   dst        = (const int*)d_in[2];
    const float* W_init     = (const float*)d_in[3];
    const float* W_gc       = (const float*)d_in[4];
    const float* b_gc       = (const float*)d_in[5];
    const float* W_res      = (const float*)d_in[6];
    const float* b_res      = (const float*)d_in[7];

    const size_t HB_BYTES  = (size_t)N_NODES * DIM * sizeof(unsigned short);
    const size_t RP_BYTES  = ((size_t)(N_NODES + 1) * 4 + 255) & ~255ull;
    const size_t DEG_BYTES = ((size_t)N_NODES * 4 + 255) & ~255ull;
    const size_t CUR_BYTES = DEG_BYTES;
    const size_t BS_BYTES  = (((size_t)(N_NODES / 256)) * 4 + 255) & ~255ull;
    const size_t EIDX_BYTES = (size_t)N_EDGES * 4;
    const size_t NEED = 2 * HB_BYTES + RP_BYTES + DEG_BYTES + CUR_BYTES + BS_BYTES + EIDX_BYTES;

    if (ws_size >= NEED) {
        char* w = (char*)d_ws;
        unsigned short* Ha = (unsigned short*)w;      w += HB_BYTES;
        unsigned short* Hb = (unsigned short*)w;      w += HB_BYTES;
        int* rowptr = (int*)w;                        w += RP_BYTES;
        int* small  = (int*)w;                        w += DEG_BYTES;
        int* wtarea = (int*)w;                        w += CUR_BYTES;
        w += BS_BYTES;
        int* eidx   = (int*)w;

        int* ccnt       = small;
        int* bcur       = small + NCHUNK;
        int* bucketBase = small + 2 * NCHUNK;
        unsigned int* bedge = (unsigned int*)Hb;
        unsigned short* Wt  = (unsigned short*)wtarea;
        unsigned short* WtI = Wt + 6 * 16384;
        float* Hout = (float*)d_out;

        zero_i<<<1, 256, 0, stream>>>(small, 2 * NCHUNK);
        coarse_hist<<<EBLKS, 256, 0, stream>>>(dst, ccnt);
        coarse_scan<<<1, NCHUNK, 0, stream>>>(ccnt, bucketBase);
        bucket_pass<<<EBLKS, 256, 0, stream>>>(src, dst, bucketBase, bcur, bedge);
        csr_pass<<<NCHUNK, 512, 0, stream>>>(bedge, bucketBase, rowptr, eidx);

        wcvt<<<6 * 64, 256, 0, stream>>>(W_gc, W_res, Wt);
        wcvt_init<<<(128 * KUSE + 255) / 256, 256, 0, stream>>>(W_init, WtI);
        init_mfma<<<N_NODES / 32, 256, 0, stream>>>(node_feats, WtI, Ha);

        layer_mfma<0><<<N_NODES / 32, 256, 0, stream>>>(
            Ha, Hb, nullptr, rowptr, eidx, Wt + 0 * 16384, Wt + 3 * 16384, b_gc, b_res);
        layer_mfma<0><<<N_NODES / 32, 256, 0, stream>>>(
            Hb, Ha, nullptr, rowptr, eidx, Wt + 1 * 16384, Wt + 4 * 16384,
            b_gc + DIM, b_res + DIM);
        layer_mfma<1><<<N_NODES / 32, 256, 0, stream>>>(
            Ha, nullptr, Hout, rowptr, eidx, Wt + 2 * 16384, Wt + 5 * 16384,
            b_gc + 2 * DIM, b_res + 2 * DIM);
    } else {
        float* H   = (float*)d_out;
        float* agg = (float*)d_ws;
        const int n4 = N_NODES * DIM / 4;
        init_mm<<<N_NODES / 8, 256, 0, stream>>>(node_feats, W_init, H);
        for (int l = 0; l < N_LAYERS; ++l) {
            zero_f4<<<(n4 + 255) / 256, 256, 0, stream>>>((float4*)agg, n4);
            scatter_add<<<(N_EDGES * 32) / 256, 256, 0, stream>>>(H, src, dst, agg);
            layer_mm<<<N_NODES / 8, 256, 0, stream>>>(agg, H,
                W_gc + (size_t)l * DIM * DIM, b_gc + (size_t)l * DIM,
                W_res + (size_t)l * DIM * DIM, b_res + (size_t)l * DIM);
        }
    }
}